// Round 1
// baseline (256.190 us; speedup 1.0000x reference)
//
#include <hip/hip_runtime.h>

typedef unsigned short u16;
typedef unsigned int u32;
typedef __attribute__((ext_vector_type(8))) short bf16x8;
typedef __attribute__((ext_vector_type(4))) float f32x4;

#define DEVI static __device__ __forceinline__

DEVI float bf2f(u16 u){ u32 x = ((u32)u) << 16; float f; __builtin_memcpy(&f, &x, 4); return f; }
DEVI u16 f2bf(float f){ u32 x; __builtin_memcpy(&x, &f, 4); u32 r = x + 0x7FFFu + ((x >> 16) & 1u); return (u16)(r >> 16); }

DEVI f32x4 mfma16(bf16x8 a, bf16x8 b, f32x4 c){
  return __builtin_amdgcn_mfma_f32_16x16x32_bf16(a, b, c, 0, 0, 0);
}

typedef __attribute__((address_space(3))) u32* lds_ptr_t;
typedef const __attribute__((address_space(1))) u32* gbl_ptr_t;
DEVI void gload16(const void* g, const void* l){
  __builtin_amdgcn_global_load_lds((gbl_ptr_t)(unsigned long long)g,
                                   (lds_ptr_t)(unsigned long long)l,
                                   16, 0, 0);
}

// ---------------- elementwise converts ----------------

__global__ void cvt_x_kernel(const float* __restrict__ X, u16* __restrict__ Xb){
  int i = blockIdx.x * 256 + threadIdx.x;            // chunk of 8 floats
  const f32x4* p = (const f32x4*)X;
  f32x4 a = p[(size_t)i*2], c = p[(size_t)i*2 + 1];
  bf16x8 v;
  v[0]=(short)f2bf(a[0]); v[1]=(short)f2bf(a[1]); v[2]=(short)f2bf(a[2]); v[3]=(short)f2bf(a[3]);
  v[4]=(short)f2bf(c[0]); v[5]=(short)f2bf(c[1]); v[6]=(short)f2bf(c[2]); v[7]=(short)f2bf(c[3]);
  *(bf16x8*)(Xb + (size_t)i*8) = v;
}

// W [K=512][N] f32 -> Wt [N][512] bf16
__global__ void transpose_w(const float* __restrict__ W, u16* __restrict__ Wt, int N){
  __shared__ float tile[32][33];
  int n0 = blockIdx.x * 32, k0 = blockIdx.y * 32;
  int tx = threadIdx.x & 31, ty = threadIdx.x >> 5;  // 32 x 8
  #pragma unroll
  for (int i = 0; i < 32; i += 8)
    tile[ty + i][tx] = W[(size_t)(k0 + ty + i) * N + n0 + tx];
  __syncthreads();
  #pragma unroll
  for (int i = 0; i < 32; i += 8)
    Wt[(size_t)(n0 + ty + i) * 512 + k0 + tx] = f2bf(tile[tx][ty + i]);
}

// ---------------- GEMM: A[M][512]bf16 @ Bt[N][512]bf16^T + bias ----------------
// MODE 0: f32 out, row-major ldC=N.  MODE 1: *scale -> bf16, head-split [B][H][S][64].
template<int MODE>
__global__ __launch_bounds__(256) void gemm_bt(
    const u16* __restrict__ A, const u16* __restrict__ Bt,
    const float* __restrict__ bias, float* __restrict__ Cf, u16* __restrict__ Cq,
    int N, float scale)
{
  __shared__ __align__(16) u16 As[128*32];
  __shared__ __align__(16) u16 Bs[128*32];
  const int t = threadIdx.x, lane = t & 63, w = t >> 6;
  const int m0 = blockIdx.y * 128, n0 = blockIdx.x * 128;
  const int wr = (w >> 1) * 64, wc = (w & 1) * 64;
  const int lrow = lane & 15, lk = lane >> 4;
  const f32x4 fz = {0.f, 0.f, 0.f, 0.f};
  f32x4 acc[4][4];
  #pragma unroll
  for (int mi = 0; mi < 4; mi++)
    #pragma unroll
    for (int ni = 0; ni < 4; ni++) acc[mi][ni] = fz;

  for (int k0 = 0; k0 < 512; k0 += 32){
    #pragma unroll
    for (int r = 0; r < 2; r++){
      int idx = r*256 + t;
      int row = idx >> 2;
      int kc  = (idx & 3) ^ (row & 3);               // pre-swizzled source chunk
      gload16(A  + (size_t)(m0+row)*512 + k0 + kc*8, (const void*)(As + r*2048 + w*512));
      gload16(Bt + (size_t)(n0+row)*512 + k0 + kc*8, (const void*)(Bs + r*2048 + w*512));
    }
    __syncthreads();
    bf16x8 af[4], bfv[4];
    #pragma unroll
    for (int i = 0; i < 4; i++){
      int ra = wr + i*16 + lrow;
      af[i]  = *(const bf16x8*)(As + ra*32 + ((lk ^ (ra & 3)) * 8));
      int rb = wc + i*16 + lrow;
      bfv[i] = *(const bf16x8*)(Bs + rb*32 + ((lk ^ (rb & 3)) * 8));
    }
    #pragma unroll
    for (int mi = 0; mi < 4; mi++)
      #pragma unroll
      for (int ni = 0; ni < 4; ni++)
        acc[mi][ni] = mfma16(af[mi], bfv[ni], acc[mi][ni]);
    __syncthreads();
  }

  #pragma unroll
  for (int mi = 0; mi < 4; mi++){
    #pragma unroll
    for (int ni = 0; ni < 4; ni++){
      int gcol = n0 + wc + ni*16 + lrow;
      float bv = bias[gcol];
      #pragma unroll
      for (int r = 0; r < 4; r++){
        int grow = m0 + wr + mi*16 + lk*4 + r;
        float v = acc[mi][ni][r] + bv;
        if (MODE == 0){
          Cf[(size_t)grow * N + gcol] = v;
        } else {
          v *= scale;
          int b = grow >> 13, s = grow & 8191;
          int hh = gcol >> 6, d = gcol & 63;
          Cq[(((size_t)(b*8 + hh))*8192 + s)*64 + d] = f2bf(v);
        }
      }
    }
  }
}

// ---------------- row LayerNorm (D=512) -> bf16 head layout ----------------
__global__ __launch_bounds__(256) void ln_rows(const float* __restrict__ inp,
    const float* __restrict__ gg, const float* __restrict__ bb, u16* __restrict__ outp)
{
  const int lane = threadIdx.x & 63, w = threadIdx.x >> 6;
  const int row = blockIdx.x * 4 + w;
  const float* p = inp + (size_t)row * 512 + lane * 8;
  f32x4 a = *(const f32x4*)p;
  f32x4 c = *(const f32x4*)(p + 4);
  float x[8] = {a[0],a[1],a[2],a[3],c[0],c[1],c[2],c[3]};
  float s = 0.f, q = 0.f;
  #pragma unroll
  for (int j = 0; j < 8; j++){ s += x[j]; q += x[j]*x[j]; }
  #pragma unroll
  for (int d = 1; d < 64; d <<= 1){ s += __shfl_xor(s, d); q += __shfl_xor(q, d); }
  float mean = s * (1.f/512.f);
  float var  = q * (1.f/512.f) - mean*mean;
  float rstd = rsqrtf(var + 1e-5f);
  int c0 = lane * 8;
  bf16x8 o;
  #pragma unroll
  for (int j = 0; j < 8; j++)
    o[j] = (short)f2bf((x[j] - mean) * rstd * gg[c0+j] + bb[c0+j]);
  int b = row >> 13, si = row & 8191, hh = c0 >> 6, d = c0 & 63;
  *(bf16x8*)(outp + (((size_t)(b*8 + hh))*8192 + si)*64 + d) = o;
}

// ---------------- hs softmax over S (column softmax) ----------------
__global__ void smax_part(const float* __restrict__ hsf, float* __restrict__ cmax, float* __restrict__ csum){
  int ch = blockIdx.x, b = blockIdx.y, c = threadIdx.x;
  const float* p = hsf + (((size_t)b*8192) + ch*128)*256 + c;
  float m = -1e30f, s = 0.f;
  for (int i = 0; i < 128; i++){
    float x = p[(size_t)i*256];
    float nm = fmaxf(m, x);
    s = s*__expf(m - nm) + __expf(x - nm);
    m = nm;
  }
  cmax[((size_t)b*64 + ch)*256 + c] = m;
  csum[((size_t)b*64 + ch)*256 + c] = s;
}

__global__ void smax_comb(const float* __restrict__ cmax, const float* __restrict__ csum,
                          float* __restrict__ gmax, float* __restrict__ gsum){
  int b = blockIdx.x, c = threadIdx.x;
  float m = -1e30f, s = 0.f;
  for (int ch = 0; ch < 64; ch++){
    float cm = cmax[((size_t)b*64 + ch)*256 + c];
    float cs = csum[((size_t)b*64 + ch)*256 + c];
    float nm = fmaxf(m, cm);
    s = s*__expf(m - nm) + cs*__expf(cm - nm);
    m = nm;
  }
  gmax[b*256 + c] = m; gsum[b*256 + c] = s;
}

__global__ void smax_norm(float* __restrict__ hsf, const float* __restrict__ gmax, const float* __restrict__ gsum){
  int i = blockIdx.x * 256 + threadIdx.x;           // f32x4 chunk
  int c0 = (i * 4) & 255;
  int b  = i >> 19;
  f32x4 x = *((const f32x4*)hsf + i);
  #pragma unroll
  for (int j = 0; j < 4; j++)
    x[j] = __expf(x[j] - gmax[b*256 + c0 + j]) / gsum[b*256 + c0 + j];
  *((f32x4*)hsf + i) = x;
}

// ---------------- compressed K_c/V_c partial sums ----------------
__global__ __launch_bounds__(256) void cmp_accum(const float* __restrict__ probs,
    const u16* __restrict__ Kb, const u16* __restrict__ Vb,
    float* __restrict__ pK, float* __restrict__ pV)
{
  __shared__ float Pls[64*32];
  __shared__ __align__(16) u16 Kl[64*64];
  __shared__ __align__(16) u16 Vl[64*64];
  const int sch = blockIdx.x, bh = blockIdx.y;
  const int b = bh >> 3, h = bh & 7;
  const int t = threadIdx.x;
  const int l = t >> 3, d0 = (t & 7) * 8;
  float aK[8], aV[8];
  #pragma unroll
  for (int j = 0; j < 8; j++){ aK[j] = 0.f; aV[j] = 0.f; }

  for (int sub = 0; sub < 4; sub++){
    int s0 = sch*256 + sub*64;
    {
      int row = t >> 2, c0 = (t & 3) * 8;
      const float* src = probs + ((size_t)b*8192 + s0 + row)*256 + h*32 + c0;
      *(f32x4*)&Pls[row*32 + c0]     = *(const f32x4*)src;
      *(f32x4*)&Pls[row*32 + c0 + 4] = *(const f32x4*)(src + 4);
    }
    {
      int row = t >> 2, e0 = (t & 3) * 16;
      const u16* ks = Kb + ((size_t)bh*8192 + s0 + row)*64 + e0;
      const u16* vs = Vb + ((size_t)bh*8192 + s0 + row)*64 + e0;
      *(bf16x8*)&Kl[row*64 + e0]     = *(const bf16x8*)ks;
      *(bf16x8*)&Kl[row*64 + e0 + 8] = *(const bf16x8*)(ks + 8);
      *(bf16x8*)&Vl[row*64 + e0]     = *(const bf16x8*)vs;
      *(bf16x8*)&Vl[row*64 + e0 + 8] = *(const bf16x8*)(vs + 8);
    }
    __syncthreads();
    for (int si = 0; si < 64; si++){
      float p = Pls[si*32 + l];
      bf16x8 kv = *(const bf16x8*)&Kl[si*64 + d0];
      bf16x8 vv = *(const bf16x8*)&Vl[si*64 + d0];
      #pragma unroll
      for (int j = 0; j < 8; j++){
        aK[j] += p * bf2f((u16)kv[j]);
        aV[j] += p * bf2f((u16)vv[j]);
      }
    }
    __syncthreads();
  }
  size_t base = ((size_t)bh*32 + sch)*2048 + l*64 + d0;
  #pragma unroll
  for (int j = 0; j < 8; j++){ pK[base + j] = aK[j]; pV[base + j] = aV[j]; }
}

// ---------------- reduce partials + LN_s -> bf16 [B][H][32][64] ----------------
__global__ __launch_bounds__(256) void ln_c_kernel(const float* __restrict__ pK, const float* __restrict__ pV,
    const float* __restrict__ gg, const float* __restrict__ bb,
    u16* __restrict__ Kcb, u16* __restrict__ Vcb)
{
  __shared__ float red[4][4];
  const int b = blockIdx.x >> 5, l = blockIdx.x & 31;
  const int t = threadIdx.x, lane = t & 63, w = t >> 6;
  float xk[2], xv[2];
  #pragma unroll
  for (int q2 = 0; q2 < 2; q2++){
    int c = t + q2*256;
    int hh = c >> 6, d = c & 63;
    float sk = 0.f, sv = 0.f;
    for (int ch = 0; ch < 32; ch++){
      size_t idx = (((size_t)(b*8 + hh)*32 + ch)*2048) + l*64 + d;
      sk += pK[idx]; sv += pV[idx];
    }
    xk[q2] = sk; xv[q2] = sv;
  }
  float s1 = xk[0]+xk[1], q1 = xk[0]*xk[0]+xk[1]*xk[1];
  float s2 = xv[0]+xv[1], q2s = xv[0]*xv[0]+xv[1]*xv[1];
  #pragma unroll
  for (int d2 = 1; d2 < 64; d2 <<= 1){
    s1 += __shfl_xor(s1, d2); q1 += __shfl_xor(q1, d2);
    s2 += __shfl_xor(s2, d2); q2s += __shfl_xor(q2s, d2);
  }
  if (lane == 0){ red[0][w]=s1; red[1][w]=q1; red[2][w]=s2; red[3][w]=q2s; }
  __syncthreads();
  s1 = red[0][0]+red[0][1]+red[0][2]+red[0][3];
  q1 = red[1][0]+red[1][1]+red[1][2]+red[1][3];
  s2 = red[2][0]+red[2][1]+red[2][2]+red[2][3];
  q2s = red[3][0]+red[3][1]+red[3][2]+red[3][3];
  float mk = s1*(1.f/512.f), vk = q1*(1.f/512.f) - mk*mk, rk = rsqrtf(vk + 1e-5f);
  float mv = s2*(1.f/512.f), vvv = q2s*(1.f/512.f) - mv*mv, rv = rsqrtf(vvv + 1e-5f);
  #pragma unroll
  for (int q2 = 0; q2 < 2; q2++){
    int c = t + q2*256;
    int hh = c >> 6, d = c & 63;
    size_t o = (((size_t)(b*8 + hh))*32 + l)*64 + d;
    Kcb[o] = f2bf((xk[q2]-mk)*rk*gg[c] + bb[c]);
    Vcb[o] = f2bf((xv[q2]-mv)*rv*gg[c] + bb[c]);
  }
}

// ---------------- fused long-short attention per (b,h,g) ----------------
__global__ __launch_bounds__(256, 1) void attn_kernel(
    const u16* __restrict__ Qb, const u16* __restrict__ Kb, const u16* __restrict__ Vb,
    const u16* __restrict__ Kcb, const u16* __restrict__ Vcb, u16* __restrict__ Cb)
{
  __shared__ __align__(16) u16 Kt[256*64];     // swizzled window K
  __shared__ __align__(16) u16 Kcs[32*64];     // swizzled compressed K
  __shared__ __align__(16) u16 Vt[64*296];     // V^T: [d][k], k 0..31 = Vc, 32..287 = window
  __shared__ __align__(16) u16 Pl[128*296];    // probs bf16, padded row stride

  const int g = blockIdx.x, h = blockIdx.y, b = blockIdx.z;
  const int t = threadIdx.x, lane = t & 63, w = t >> 6;
  const int bh = b*8 + h;
  const int s0 = g*128 - 64;
  const int lrow = lane & 15, lk = lane >> 4;
  const bf16x8 bz = {0,0,0,0,0,0,0,0};
  const f32x4 fz = {0.f,0.f,0.f,0.f};

  #pragma unroll
  for (int i = 0; i < 8; i++){
    int idx = i*256 + t;
    int row = idx >> 3, kc = idx & 7;
    int sk = s0 + row;
    bf16x8 v = bz;
    if (sk >= 0 && sk < 8192) v = *(const bf16x8*)(Kb + ((size_t)bh*8192 + sk)*64 + kc*8);
    int off = row*128 + kc*16; off ^= (row & 7) << 4;
    *(bf16x8*)((char*)Kt + off) = v;
  }
  {
    int row = t >> 3, kc = t & 7;
    bf16x8 v = *(const bf16x8*)(Kcb + ((size_t)bh*32 + row)*64 + kc*8);
    int off = row*128 + kc*16; off ^= (row & 7) << 4;
    *(bf16x8*)((char*)Kcs + off) = v;
  }
  {
    int row = t >> 3, kc = t & 7;   // row = l
    bf16x8 v = *(const bf16x8*)(Vcb + ((size_t)bh*32 + row)*64 + kc*8);
    #pragma unroll
    for (int j = 0; j < 8; j++) Vt[(kc*8 + j)*296 + row] = (u16)v[j];
  }
  #pragma unroll
  for (int i = 0; i < 8; i++){
    int idx = i*256 + t;
    int row = idx >> 3, kc = idx & 7;
    int sk = s0 + row;
    bf16x8 v = bz;
    if (sk >= 0 && sk < 8192) v = *(const bf16x8*)(Vb + ((size_t)bh*8192 + sk)*64 + kc*8);
    #pragma unroll
    for (int j = 0; j < 8; j++) Vt[(kc*8 + j)*296 + 32 + row] = (u16)v[j];
  }

  bf16x8 qf[2][2];
  const int qrow = g*128 + w*32;
  #pragma unroll
  for (int sm = 0; sm < 2; sm++)
    #pragma unroll
    for (int ks = 0; ks < 2; ks++)
      qf[sm][ks] = *(const bf16x8*)(Qb + ((size_t)bh*8192 + qrow + sm*16 + lrow)*64 + ks*32 + lk*8);

  __syncthreads();

  // QK^T over 288 columns (2 subtiles compressed + 16 window)
  f32x4 sc[2][18];
  #pragma unroll
  for (int sm = 0; sm < 2; sm++)
    #pragma unroll
    for (int j = 0; j < 18; j++) sc[sm][j] = fz;

  #pragma unroll
  for (int j = 0; j < 18; j++){
    #pragma unroll
    for (int ks = 0; ks < 2; ks++){
      bf16x8 bv;
      if (j < 2){
        int r = j*16 + lrow;
        int off = r*128 + (ks*32 + lk*8)*2; off ^= (r & 7) << 4;
        bv = *(const bf16x8*)((char*)Kcs + off);
      } else {
        int r = (j-2)*16 + lrow;
        int off = r*128 + (ks*32 + lk*8)*2; off ^= (r & 7) << 4;
        bv = *(const bf16x8*)((char*)Kt + off);
      }
      sc[0][j] = mfma16(qf[0][ks], bv, sc[0][j]);
      sc[1][j] = mfma16(qf[1][ks], bv, sc[1][j]);
    }
  }

  // mask out-of-sequence window columns
  #pragma unroll
  for (int j = 2; j < 18; j++){
    int sk = s0 + (j-2)*16 + lrow;
    if (sk < 0 || sk >= 8192){
      #pragma unroll
      for (int r = 0; r < 4; r++){ sc[0][j][r] = -1e30f; sc[1][j][r] = -1e30f; }
    }
  }

  // per-row softmax (row spread across 16 lanes x 18 frags)
  #pragma unroll
  for (int sm = 0; sm < 2; sm++){
    #pragma unroll
    for (int r = 0; r < 4; r++){
      float m = -1e30f;
      #pragma unroll
      for (int j = 0; j < 18; j++) m = fmaxf(m, sc[sm][j][r]);
      #pragma unroll
      for (int d2 = 1; d2 < 16; d2 <<= 1) m = fmaxf(m, __shfl_xor(m, d2));
      float ssum = 0.f;
      #pragma unroll
      for (int j = 0; j < 18; j++){
        float e = __expf(sc[sm][j][r] - m);
        sc[sm][j][r] = e; ssum += e;
      }
      #pragma unroll
      for (int d2 = 1; d2 < 16; d2 <<= 1) ssum += __shfl_xor(ssum, d2);
      float inv = 1.0f / ssum;
      #pragma unroll
      for (int j = 0; j < 18; j++) sc[sm][j][r] *= inv;
    }
  }

  #pragma unroll
  for (int sm = 0; sm < 2; sm++)
    #pragma unroll
    for (int j = 0; j < 18; j++)
      #pragma unroll
      for (int r = 0; r < 4; r++){
        int row = w*32 + sm*16 + lk*4 + r;
        int col = j*16 + lrow;
        Pl[row*296 + col] = f2bf(sc[sm][j][r]);
      }

  __syncthreads();

  // P @ [Vc; V_window]
  f32x4 ao[2][4];
  #pragma unroll
  for (int sm = 0; sm < 2; sm++)
    #pragma unroll
    for (int nj = 0; nj < 4; nj++) ao[sm][nj] = fz;

  #pragma unroll
  for (int ks = 0; ks < 9; ks++){
    bf16x8 pa0 = *(const bf16x8*)(Pl + (w*32 + lrow)*296 + ks*32 + lk*8);
    bf16x8 pa1 = *(const bf16x8*)(Pl + (w*32 + 16 + lrow)*296 + ks*32 + lk*8);
    #pragma unroll
    for (int nj = 0; nj < 4; nj++){
      bf16x8 bv = *(const bf16x8*)(Vt + (nj*16 + lrow)*296 + ks*32 + lk*8);
      ao[0][nj] = mfma16(pa0, bv, ao[0][nj]);
      ao[1][nj] = mfma16(pa1, bv, ao[1][nj]);
    }
  }

  #pragma unroll
  for (int sm = 0; sm < 2; sm++)
    #pragma unroll
    for (int nj = 0; nj < 4; nj++)
      #pragma unroll
      for (int r = 0; r < 4; r++){
        int srow = g*128 + w*32 + sm*16 + lk*4 + r;
        int col = h*64 + nj*16 + lrow;
        Cb[((size_t)b*8192 + srow)*512 + col] = f2bf(ao[sm][nj][r]);
      }
}

// ---------------- workspace layout ----------------
constexpr size_t OFF_XB   = 0;                         // 16777216
constexpr size_t OFF_WQT  = OFF_XB  + 16777216;        // 524288
constexpr size_t OFF_WKT  = OFF_WQT + 524288;
constexpr size_t OFF_WVT  = OFF_WKT + 524288;
constexpr size_t OFF_WOT  = OFF_WVT + 524288;
constexpr size_t OFF_WDT  = OFF_WOT + 524288;          // 262144
constexpr size_t OFF_QB   = OFF_WDT + 262144;          // 16777216
constexpr size_t OFF_KB   = OFF_QB  + 16777216;
constexpr size_t OFF_VB   = OFF_KB  + 16777216;
constexpr size_t OFF_TMPF = OFF_VB  + 16777216;        // 33554432 (f32 pre-LN; later reused as Cb)
constexpr size_t OFF_CB   = OFF_TMPF;
constexpr size_t OFF_HSF  = OFF_TMPF + 33554432;       // 16777216
constexpr size_t OFF_CMX  = OFF_HSF + 16777216;        // 131072
constexpr size_t OFF_CSM  = OFF_CMX + 131072;
constexpr size_t OFF_GMX  = OFF_CSM + 131072;          // 2048
constexpr size_t OFF_GSM  = OFF_GMX + 2048;
constexpr size_t OFF_PK   = OFF_GSM + 2048;            // 4194304
constexpr size_t OFF_PV   = OFF_PK  + 4194304;
constexpr size_t OFF_KCB  = OFF_PV  + 4194304;         // 65536
constexpr size_t OFF_VCB  = OFF_KCB + 65536;

extern "C" void kernel_launch(void* const* d_in, const int* in_sizes, int n_in,
                              void* d_out, int out_size, void* d_ws, size_t ws_size,
                              hipStream_t stream)
{
  const float* X    = (const float*)d_in[0];
  const float* Wq   = (const float*)d_in[2];
  const float* Wqb  = (const float*)d_in[3];
  const float* Wk   = (const float*)d_in[4];
  const float* Wkb  = (const float*)d_in[5];
  const float* Wv   = (const float*)d_in[6];
  const float* Wvb  = (const float*)d_in[7];
  const float* Wo   = (const float*)d_in[8];
  const float* Wob  = (const float*)d_in[9];
  const float* lnlg = (const float*)d_in[10];
  const float* lnlb = (const float*)d_in[11];
  const float* lnsg = (const float*)d_in[12];
  const float* lnsb = (const float*)d_in[13];
  const float* Wd   = (const float*)d_in[14];
  const float* Wdb  = (const float*)d_in[15];
  float* out = (float*)d_out;

  char* ws = (char*)d_ws;
  u16*   Xb   = (u16*)(ws + OFF_XB);
  u16*   WqT  = (u16*)(ws + OFF_WQT);
  u16*   WkT  = (u16*)(ws + OFF_WKT);
  u16*   WvT  = (u16*)(ws + OFF_WVT);
  u16*   WoT  = (u16*)(ws + OFF_WOT);
  u16*   WdT  = (u16*)(ws + OFF_WDT);
  u16*   Qb   = (u16*)(ws + OFF_QB);
  u16*   Kb   = (u16*)(ws + OFF_KB);
  u16*   Vb   = (u16*)(ws + OFF_VB);
  float* tmpf = (float*)(ws + OFF_TMPF);
  u16*   Cbp  = (u16*)(ws + OFF_CB);
  float* hsf  = (float*)(ws + OFF_HSF);
  float* cmx  = (float*)(ws + OFF_CMX);
  float* csm  = (float*)(ws + OFF_CSM);
  float* gmx  = (float*)(ws + OFF_GMX);
  float* gsm  = (float*)(ws + OFF_GSM);
  float* pK   = (float*)(ws + OFF_PK);
  float* pV   = (float*)(ws + OFF_PV);
  u16*   Kcb  = (u16*)(ws + OFF_KCB);
  u16*   Vcb  = (u16*)(ws + OFF_VCB);

  const float SCALE = 0.125f;

  cvt_x_kernel<<<dim3(4096), dim3(256), 0, stream>>>(X, Xb);
  transpose_w<<<dim3(16,16), dim3(256), 0, stream>>>(Wq, WqT, 512);
  transpose_w<<<dim3(16,16), dim3(256), 0, stream>>>(Wk, WkT, 512);
  transpose_w<<<dim3(16,16), dim3(256), 0, stream>>>(Wv, WvT, 512);
  transpose_w<<<dim3(16,16), dim3(256), 0, stream>>>(Wo, WoT, 512);
  transpose_w<<<dim3(8,16),  dim3(256), 0, stream>>>(Wd, WdT, 256);

  gemm_bt<1><<<dim3(4,128), dim3(256), 0, stream>>>(Xb, WqT, Wqb, nullptr, Qb, 512, SCALE);
  gemm_bt<0><<<dim3(4,128), dim3(256), 0, stream>>>(Xb, WkT, Wkb, tmpf, nullptr, 512, 1.f);
  ln_rows<<<dim3(4096), dim3(256), 0, stream>>>(tmpf, lnlg, lnlb, Kb);
  gemm_bt<0><<<dim3(4,128), dim3(256), 0, stream>>>(Xb, WvT, Wvb, tmpf, nullptr, 512, 1.f);
  ln_rows<<<dim3(4096), dim3(256), 0, stream>>>(tmpf, lnlg, lnlb, Vb);
  gemm_bt<0><<<dim3(2,128), dim3(256), 0, stream>>>(Xb, WdT, Wdb, hsf, nullptr, 256, 1.f);

  smax_part<<<dim3(64,2), dim3(256), 0, stream>>>(hsf, cmx, csm);
  smax_comb<<<dim3(2), dim3(256), 0, stream>>>(cmx, csm, gmx, gsm);
  smax_norm<<<dim3(4096), dim3(256), 0, stream>>>(hsf, gmx, gsm);

  cmp_accum<<<dim3(32,16), dim3(256), 0, stream>>>(hsf, Kb, Vb, pK, pV);
  ln_c_kernel<<<dim3(64), dim3(256), 0, stream>>>(pK, pV, lnsg, lnsb, Kcb, Vcb);

  attn_kernel<<<dim3(64,8,2), dim3(256), 0, stream>>>(Qb, Kb, Vb, Kcb, Vcb, Cbp);

  gemm_bt<0><<<dim3(4,128), dim3(256), 0, stream>>>(Cbp, WoT, Wob, out, nullptr, 512, 1.f);
}

// Round 2
// 238.463 us; speedup vs baseline: 1.0743x; 1.0743x over previous
//
#include <hip/hip_runtime.h>

typedef unsigned short u16;
typedef unsigned int u32;
typedef __attribute__((ext_vector_type(8))) short bf16x8;
typedef __attribute__((ext_vector_type(4))) float f32x4;

#define DEVI static __device__ __forceinline__

DEVI float bf2f(u16 u){ u32 x = ((u32)u) << 16; float f; __builtin_memcpy(&f, &x, 4); return f; }
DEVI u16 f2bf(float f){ u32 x; __builtin_memcpy(&x, &f, 4); u32 r = x + 0x7FFFu + ((x >> 16) & 1u); return (u16)(r >> 16); }
DEVI u32 pk2(float a, float b){ return ((u32)f2bf(b) << 16) | (u32)f2bf(a); }

DEVI f32x4 mfma16(bf16x8 a, bf16x8 b, f32x4 c){
  return __builtin_amdgcn_mfma_f32_16x16x32_bf16(a, b, c, 0, 0, 0);
}

typedef __attribute__((address_space(3))) u32* lds_ptr_t;
typedef const __attribute__((address_space(1))) u32* gbl_ptr_t;
DEVI void gload16(const void* g, const void* l){
  __builtin_amdgcn_global_load_lds((gbl_ptr_t)(unsigned long long)g,
                                   (lds_ptr_t)(unsigned long long)l,
                                   16, 0, 0);
}

// ---------------- elementwise converts ----------------

__global__ void cvt_x_kernel(const float* __restrict__ X, u16* __restrict__ Xb){
  int i = blockIdx.x * 256 + threadIdx.x;            // chunk of 8 floats
  const f32x4* p = (const f32x4*)X;
  f32x4 a = p[(size_t)i*2], c = p[(size_t)i*2 + 1];
  bf16x8 v;
  v[0]=(short)f2bf(a[0]); v[1]=(short)f2bf(a[1]); v[2]=(short)f2bf(a[2]); v[3]=(short)f2bf(a[3]);
  v[4]=(short)f2bf(c[0]); v[5]=(short)f2bf(c[1]); v[6]=(short)f2bf(c[2]); v[7]=(short)f2bf(c[3]);
  *(bf16x8*)(Xb + (size_t)i*8) = v;
}

// W [K=512][N] f32 -> Wt [N][512] bf16
__global__ void transpose_w(const float* __restrict__ W, u16* __restrict__ Wt, int N){
  __shared__ float tile[32][33];
  int n0 = blockIdx.x * 32, k0 = blockIdx.y * 32;
  int tx = threadIdx.x & 31, ty = threadIdx.x >> 5;  // 32 x 8
  #pragma unroll
  for (int i = 0; i < 32; i += 8)
    tile[ty + i][tx] = W[(size_t)(k0 + ty + i) * N + n0 + tx];
  __syncthreads();
  #pragma unroll
  for (int i = 0; i < 32; i += 8)
    Wt[(size_t)(n0 + ty + i) * 512 + k0 + tx] = f2bf(tile[tx][ty + i]);
}

// ---------------- GEMM: A[M][512]bf16 @ Bt[N][512]bf16^T + bias ----------------
template<int MODE>
__global__ __launch_bounds__(256) void gemm_bt(
    const u16* __restrict__ A, const u16* __restrict__ Bt,
    const float* __restrict__ bias, float* __restrict__ Cf, u16* __restrict__ Cq,
    int N, float scale)
{
  __shared__ __align__(16) u16 As[128*32];
  __shared__ __align__(16) u16 Bs[128*32];
  const int t = threadIdx.x, lane = t & 63, w = t >> 6;
  const int m0 = blockIdx.y * 128, n0 = blockIdx.x * 128;
  const int wr = (w >> 1) * 64, wc = (w & 1) * 64;
  const int lrow = lane & 15, lk = lane >> 4;
  const f32x4 fz = {0.f, 0.f, 0.f, 0.f};
  f32x4 acc[4][4];
  #pragma unroll
  for (int mi = 0; mi < 4; mi++)
    #pragma unroll
    for (int ni = 0; ni < 4; ni++) acc[mi][ni] = fz;

  for (int k0 = 0; k0 < 512; k0 += 32){
    #pragma unroll
    for (int r = 0; r < 2; r++){
      int idx = r*256 + t;
      int row = idx >> 2;
      int kc  = (idx & 3) ^ (row & 3);
      gload16(A  + (size_t)(m0+row)*512 + k0 + kc*8, (const void*)(As + r*2048 + w*512));
      gload16(Bt + (size_t)(n0+row)*512 + k0 + kc*8, (const void*)(Bs + r*2048 + w*512));
    }
    __syncthreads();
    bf16x8 af[4], bfv[4];
    #pragma unroll
    for (int i = 0; i < 4; i++){
      int ra = wr + i*16 + lrow;
      af[i]  = *(const bf16x8*)(As + ra*32 + ((lk ^ (ra & 3)) * 8));
      int rb = wc + i*16 + lrow;
      bfv[i] = *(const bf16x8*)(Bs + rb*32 + ((lk ^ (rb & 3)) * 8));
    }
    #pragma unroll
    for (int mi = 0; mi < 4; mi++)
      #pragma unroll
      for (int ni = 0; ni < 4; ni++)
        acc[mi][ni] = mfma16(af[mi], bfv[ni], acc[mi][ni]);
    __syncthreads();
  }

  #pragma unroll
  for (int mi = 0; mi < 4; mi++){
    #pragma unroll
    for (int ni = 0; ni < 4; ni++){
      int gcol = n0 + wc + ni*16 + lrow;
      float bv = bias[gcol];
      #pragma unroll
      for (int r = 0; r < 4; r++){
        int grow = m0 + wr + mi*16 + lk*4 + r;
        float v = acc[mi][ni][r] + bv;
        if (MODE == 0){
          Cf[(size_t)grow * N + gcol] = v;
        } else {
          v *= scale;
          int b = grow >> 13, s = grow & 8191;
          int hh = gcol >> 6, d = gcol & 63;
          Cq[(((size_t)(b*8 + hh))*8192 + s)*64 + d] = f2bf(v);
        }
      }
    }
  }
}

// ---------------- row LayerNorm (D=512) -> bf16 head layout ----------------
__global__ __launch_bounds__(256) void ln_rows(const float* __restrict__ inp,
    const float* __restrict__ gg, const float* __restrict__ bb, u16* __restrict__ outp)
{
  const int lane = threadIdx.x & 63, w = threadIdx.x >> 6;
  const int row = blockIdx.x * 4 + w;
  const float* p = inp + (size_t)row * 512 + lane * 8;
  f32x4 a = *(const f32x4*)p;
  f32x4 c = *(const f32x4*)(p + 4);
  float x[8] = {a[0],a[1],a[2],a[3],c[0],c[1],c[2],c[3]};
  float s = 0.f, q = 0.f;
  #pragma unroll
  for (int j = 0; j < 8; j++){ s += x[j]; q += x[j]*x[j]; }
  #pragma unroll
  for (int d = 1; d < 64; d <<= 1){ s += __shfl_xor(s, d); q += __shfl_xor(q, d); }
  float mean = s * (1.f/512.f);
  float var  = q * (1.f/512.f) - mean*mean;
  float rstd = rsqrtf(var + 1e-5f);
  int c0 = lane * 8;
  bf16x8 o;
  #pragma unroll
  for (int j = 0; j < 8; j++)
    o[j] = (short)f2bf((x[j] - mean) * rstd * gg[c0+j] + bb[c0+j]);
  int b = row >> 13, si = row & 8191, hh = c0 >> 6, d = c0 & 63;
  *(bf16x8*)(outp + (((size_t)(b*8 + hh))*8192 + si)*64 + d) = o;
}

// ---------------- V transpose: Vb [bh][8192][64] -> VbT [bh][64][8192] ----------------
__global__ __launch_bounds__(256) void transpose_v(const u16* __restrict__ Vb, u16* __restrict__ VbT){
  __shared__ u16 tile[64][72];
  const int st = blockIdx.x, bh = blockIdx.y;
  const int t = threadIdx.x;
  {
    int row = t >> 2, cc = (t & 3) * 16;
    const u16* src = Vb + ((size_t)bh*8192 + st*64 + row)*64 + cc;
    *(bf16x8*)&tile[row][cc]     = *(const bf16x8*)src;
    *(bf16x8*)&tile[row][cc + 8] = *(const bf16x8*)(src + 8);
  }
  __syncthreads();
  {
    int d = t >> 2, sc4 = (t & 3) * 16;
    bf16x8 o0, o1;
    #pragma unroll
    for (int i = 0; i < 8; i++) o0[i] = (short)tile[sc4 + i][d];
    #pragma unroll
    for (int i = 0; i < 8; i++) o1[i] = (short)tile[sc4 + 8 + i][d];
    u16* dst = VbT + ((size_t)bh*64 + d)*8192 + st*64 + sc4;
    *(bf16x8*)dst       = o0;
    *(bf16x8*)(dst + 8) = o1;
  }
}

// ---------------- hs softmax over S (column softmax) ----------------
__global__ void smax_part(const float* __restrict__ hsf, float* __restrict__ cmax, float* __restrict__ csum){
  int ch = blockIdx.x, b = blockIdx.y, c = threadIdx.x;
  const float* p = hsf + (((size_t)b*8192) + ch*64)*256 + c;
  float m = -1e30f, s = 0.f;
  #pragma unroll 4
  for (int i = 0; i < 64; i++){
    float x = p[(size_t)i*256];
    float nm = fmaxf(m, x);
    s = s*__expf(m - nm) + __expf(x - nm);
    m = nm;
  }
  cmax[((size_t)b*128 + ch)*256 + c] = m;
  csum[((size_t)b*128 + ch)*256 + c] = s;
}

__global__ void smax_comb(const float* __restrict__ cmax, const float* __restrict__ csum,
                          float* __restrict__ gmax, float* __restrict__ gsum){
  int b = blockIdx.x, c = threadIdx.x;
  float m = -1e30f, s = 0.f;
  for (int ch = 0; ch < 128; ch++){
    float cm = cmax[((size_t)b*128 + ch)*256 + c];
    float cs = csum[((size_t)b*128 + ch)*256 + c];
    float nm = fmaxf(m, cm);
    s = s*__expf(m - nm) + cs*__expf(cm - nm);
    m = nm;
  }
  gmax[b*256 + c] = m; gsum[b*256 + c] = s;
}

// ---------------- compressed K_c/V_c partial sums (softmax-normalize fused) ----------------
__global__ __launch_bounds__(256) void cmp_accum(const float* __restrict__ hsf,
    const float* __restrict__ gmax, const float* __restrict__ gsum,
    const u16* __restrict__ Kb, const u16* __restrict__ Vb,
    float* __restrict__ pK, float* __restrict__ pV)
{
  __shared__ float Pls[64*36];
  __shared__ __align__(16) float Klf[64*68];
  __shared__ __align__(16) float Vlf[64*68];
  const int sch = blockIdx.x, bh = blockIdx.y;
  const int b = bh >> 3, h = bh & 7;
  const int t = threadIdx.x;
  const int l = t >> 3, d0 = (t & 7) * 8;
  const int c0 = (t & 3) * 8;
  float gm[8], gi[8];
  #pragma unroll
  for (int j = 0; j < 8; j++){
    int c = h*32 + c0 + j;
    gm[j] = gmax[b*256 + c];
    gi[j] = 1.0f / gsum[b*256 + c];
  }
  float aK[8], aV[8];
  #pragma unroll
  for (int j = 0; j < 8; j++){ aK[j] = 0.f; aV[j] = 0.f; }

  for (int sub = 0; sub < 4; sub++){
    int s0 = sch*256 + sub*64;
    {
      int row = t >> 2;
      const float* src = hsf + ((size_t)b*8192 + s0 + row)*256 + h*32 + c0;
      f32x4 x0 = *(const f32x4*)src, x1 = *(const f32x4*)(src + 4);
      #pragma unroll
      for (int j = 0; j < 4; j++){
        Pls[row*36 + c0 + j]     = __expf(x0[j] - gm[j])   * gi[j];
        Pls[row*36 + c0 + 4 + j] = __expf(x1[j] - gm[4+j]) * gi[4+j];
      }
    }
    {
      int row = t >> 2, e0 = (t & 3) * 16;
      const u16* ks = Kb + ((size_t)bh*8192 + s0 + row)*64 + e0;
      const u16* vs = Vb + ((size_t)bh*8192 + s0 + row)*64 + e0;
      bf16x8 k0 = *(const bf16x8*)ks, k1 = *(const bf16x8*)(ks + 8);
      bf16x8 v0 = *(const bf16x8*)vs, v1 = *(const bf16x8*)(vs + 8);
      #pragma unroll
      for (int j = 0; j < 8; j++){
        Klf[row*68 + e0 + j]     = bf2f((u16)k0[j]);
        Klf[row*68 + e0 + 8 + j] = bf2f((u16)k1[j]);
        Vlf[row*68 + e0 + j]     = bf2f((u16)v0[j]);
        Vlf[row*68 + e0 + 8 + j] = bf2f((u16)v1[j]);
      }
    }
    __syncthreads();
    #pragma unroll 2
    for (int si = 0; si < 64; si++){
      float p = Pls[si*36 + l];
      f32x4 ka = *(const f32x4*)&Klf[si*68 + d0];
      f32x4 kb = *(const f32x4*)&Klf[si*68 + d0 + 4];
      f32x4 va = *(const f32x4*)&Vlf[si*68 + d0];
      f32x4 vb = *(const f32x4*)&Vlf[si*68 + d0 + 4];
      #pragma unroll
      for (int j = 0; j < 4; j++){
        aK[j]   += p * ka[j];
        aK[4+j] += p * kb[j];
        aV[j]   += p * va[j];
        aV[4+j] += p * vb[j];
      }
    }
    __syncthreads();
  }
  size_t base = ((size_t)bh*32 + sch)*2048 + l*64 + d0;
  #pragma unroll
  for (int j = 0; j < 8; j++){ pK[base + j] = aK[j]; pV[base + j] = aV[j]; }
}

// ---------------- reduce partials + LN_s -> Kcb [bh][32][64], VcT [bh][64][32] ----------------
__global__ __launch_bounds__(256) void ln_c_kernel(const float* __restrict__ pK, const float* __restrict__ pV,
    const float* __restrict__ gg, const float* __restrict__ bb,
    u16* __restrict__ Kcb, u16* __restrict__ VcT)
{
  __shared__ float red[4][4];
  const int b = blockIdx.x >> 5, l = blockIdx.x & 31;
  const int t = threadIdx.x, lane = t & 63, w = t >> 6;
  float xk[2], xv[2];
  #pragma unroll
  for (int q2 = 0; q2 < 2; q2++){
    int c = t + q2*256;
    int hh = c >> 6, d = c & 63;
    float sk = 0.f, sv = 0.f;
    for (int ch = 0; ch < 32; ch++){
      size_t idx = (((size_t)(b*8 + hh)*32 + ch)*2048) + l*64 + d;
      sk += pK[idx]; sv += pV[idx];
    }
    xk[q2] = sk; xv[q2] = sv;
  }
  float s1 = xk[0]+xk[1], q1 = xk[0]*xk[0]+xk[1]*xk[1];
  float s2 = xv[0]+xv[1], q2s = xv[0]*xv[0]+xv[1]*xv[1];
  #pragma unroll
  for (int d2 = 1; d2 < 64; d2 <<= 1){
    s1 += __shfl_xor(s1, d2); q1 += __shfl_xor(q1, d2);
    s2 += __shfl_xor(s2, d2); q2s += __shfl_xor(q2s, d2);
  }
  if (lane == 0){ red[0][w]=s1; red[1][w]=q1; red[2][w]=s2; red[3][w]=q2s; }
  __syncthreads();
  s1 = red[0][0]+red[0][1]+red[0][2]+red[0][3];
  q1 = red[1][0]+red[1][1]+red[1][2]+red[1][3];
  s2 = red[2][0]+red[2][1]+red[2][2]+red[2][3];
  q2s = red[3][0]+red[3][1]+red[3][2]+red[3][3];
  float mk = s1*(1.f/512.f), vk = q1*(1.f/512.f) - mk*mk, rk = rsqrtf(vk + 1e-5f);
  float mv = s2*(1.f/512.f), vvv = q2s*(1.f/512.f) - mv*mv, rv = rsqrtf(vvv + 1e-5f);
  #pragma unroll
  for (int q2 = 0; q2 < 2; q2++){
    int c = t + q2*256;
    int hh = c >> 6, d = c & 63;
    Kcb[(((size_t)(b*8 + hh))*32 + l)*64 + d] = f2bf((xk[q2]-mk)*rk*gg[c] + bb[c]);
    VcT[(((size_t)(b*8 + hh))*64 + d)*32 + l] = f2bf((xv[q2]-mv)*rv*gg[c] + bb[c]);
  }
}

// ---------------- fused long-short attention per (b,h,g), swapped-operand form ----------------
// S^T = mfma(K, Q^T); softmax per-lane; O^T = mfma(V^T, P^T).
// LDS: Kt [288][64] swizzled (36864 B) | Vt [64][296] (37888 B); Pl [128][104] aliases Kt.
__global__ __launch_bounds__(512, 4) void attn2_kernel(
    const u16* __restrict__ Qb, const u16* __restrict__ Kb, const u16* __restrict__ Kcb,
    const u16* __restrict__ VbT, const u16* __restrict__ VcT, u16* __restrict__ Cb)
{
  __shared__ __align__(16) char smem[74752];
  u16* Vt = (u16*)(smem + 36864);
  u16* Pl = (u16*)smem;

  const int g = blockIdx.x, h = blockIdx.y, b = blockIdx.z;
  const int bh = b*8 + h;
  const int t = threadIdx.x, lane = t & 63, w = t >> 6;
  const int lrow = lane & 15, lk = lane >> 4;
  const int s0 = g*128 - 64;
  const bf16x8 bz = {0,0,0,0,0,0,0,0};
  const f32x4 fz = {0.f,0.f,0.f,0.f};

  // ---- stage K (window rows 0..255 from Kb, compressed rows 256..287 from Kcb)
  #pragma unroll
  for (int it = 0; it < 5; it++){
    int idx = it*512 + t;
    if (idx < 2304){
      int row = idx >> 3, kc = idx & 7;
      bf16x8 v = bz;
      if (row < 256){
        int sk = s0 + row;
        if (sk >= 0 && sk < 8192) v = *(const bf16x8*)(Kb + ((size_t)bh*8192 + sk)*64 + kc*8);
      } else {
        v = *(const bf16x8*)(Kcb + ((size_t)bh*32 + (row - 256))*64 + kc*8);
      }
      int off = row*128 + kc*16; off ^= (row & 7) << 4;
      *(bf16x8*)(smem + off) = v;
    }
  }
  // ---- stage V^T window cols 0..255 (from VbT), comp cols 256..287 (from VcT)
  #pragma unroll
  for (int it = 0; it < 4; it++){
    int idx = it*512 + t;
    int d = idx >> 5, cc = idx & 31;
    int sk = s0 + cc*8;
    bf16x8 v = bz;
    if (sk >= 0 && sk < 8192) v = *(const bf16x8*)(VbT + ((size_t)bh*64 + d)*8192 + sk);
    *(bf16x8*)(Vt + d*296 + cc*8) = v;
  }
  if (t < 256){
    int d = t >> 2, cc = t & 3;
    bf16x8 v = *(const bf16x8*)(VcT + ((size_t)bh*64 + d)*32 + cc*8);
    *(bf16x8*)(Vt + d*296 + 256 + cc*8) = v;
  }
  // ---- Q fragments (B-operand of swapped QK^T): lane holds Q[q=w*16+lrow][dh 8-contig]
  bf16x8 qf[2];
  #pragma unroll
  for (int ks = 0; ks < 2; ks++)
    qf[ks] = *(const bf16x8*)(Qb + ((size_t)bh*8192 + g*128 + w*16 + lrow)*64 + ks*32 + lk*8);

  __syncthreads();

  // ---- QK^T (swapped): sc[j] holds S^T rows s=16j+4lk+r, col q=lrow
  f32x4 sc[18];
  #pragma unroll
  for (int j = 0; j < 18; j++) sc[j] = fz;
  #pragma unroll
  for (int j = 0; j < 18; j++){
    int row = j*16 + lrow;
    #pragma unroll
    for (int ks = 0; ks < 2; ks++){
      int off = row*128 + ks*64 + lk*16; off ^= (row & 7) << 4;
      bf16x8 kf = *(const bf16x8*)(smem + off);
      sc[j] = mfma16(kf, qf[ks], sc[j]);
    }
  }

  // ---- mask out-of-sequence window rows (bounds are multiples of 4 -> whole reg-group)
  #pragma unroll
  for (int j = 0; j < 16; j++){
    int sb = s0 + j*16 + lk*4;
    if (sb < 0 || sb >= 8192){
      sc[j][0] = -1e30f; sc[j][1] = -1e30f; sc[j][2] = -1e30f; sc[j][3] = -1e30f;
    }
  }

  // ---- softmax: lane owns 72 values of column q; cross-lane over lk via xor 16/32
  float m = -1e30f;
  #pragma unroll
  for (int j = 0; j < 18; j++)
    m = fmaxf(m, fmaxf(fmaxf(sc[j][0], sc[j][1]), fmaxf(sc[j][2], sc[j][3])));
  m = fmaxf(m, __shfl_xor(m, 16));
  m = fmaxf(m, __shfl_xor(m, 32));
  float ssum = 0.f;
  #pragma unroll
  for (int j = 0; j < 18; j++){
    #pragma unroll
    for (int r = 0; r < 4; r++){
      float e = __expf(sc[j][r] - m);
      sc[j][r] = e; ssum += e;
    }
  }
  ssum += __shfl_xor(ssum, 16);
  ssum += __shfl_xor(ssum, 32);
  float inv = 1.0f / ssum;

  // ---- PV in 3 chunks of 96 s-cols; P^T staged in Pl (aliases dead Kt)
  f32x4 ao[4];
  #pragma unroll
  for (int nj = 0; nj < 4; nj++) ao[nj] = fz;
  const int prow = w*16 + lrow;

  #pragma unroll
  for (int c = 0; c < 3; c++){
    __syncthreads();   // Kt reads done (c=0) / previous Pl reads done (c>0)
    #pragma unroll
    for (int jj = 0; jj < 6; jj++){
      int j = c*6 + jj;
      u32* dst = (u32*)(Pl + prow*104 + jj*16 + lk*4);
      dst[0] = pk2(sc[j][0], sc[j][1]);
      dst[1] = pk2(sc[j][2], sc[j][3]);
    }
    __syncthreads();
    #pragma unroll
    for (int ksl = 0; ksl < 3; ksl++){
      bf16x8 pb = *(const bf16x8*)(Pl + prow*104 + ksl*32 + lk*8);
      #pragma unroll
      for (int nj = 0; nj < 4; nj++){
        bf16x8 av = *(const bf16x8*)(Vt + (nj*16 + lrow)*296 + c*96 + ksl*32 + lk*8);
        ao[nj] = mfma16(av, pb, ao[nj]);
      }
    }
  }

  // ---- epilogue: O^T frag: col q = lane&15, row d = nj*16 + lk*4 + r; normalize by inv
  const int qglob = g*128 + w*16 + lrow;
  #pragma unroll
  for (int nj = 0; nj < 4; nj++){
    u32* dst = (u32*)(Cb + ((size_t)b*8192 + qglob)*512 + h*64 + nj*16 + lk*4);
    dst[0] = pk2(ao[nj][0]*inv, ao[nj][1]*inv);
    dst[1] = pk2(ao[nj][2]*inv, ao[nj][3]*inv);
  }
}

// ---------------- workspace layout ----------------
constexpr size_t OFF_XB   = 0;                         // 16777216
constexpr size_t OFF_WQT  = OFF_XB  + 16777216;        // 524288
constexpr size_t OFF_WKT  = OFF_WQT + 524288;
constexpr size_t OFF_WVT  = OFF_WKT + 524288;
constexpr size_t OFF_WOT  = OFF_WVT + 524288;
constexpr size_t OFF_WDT  = OFF_WOT + 524288;          // 262144
constexpr size_t OFF_QB   = OFF_WDT + 262144;          // 16777216
constexpr size_t OFF_KB   = OFF_QB  + 16777216;
constexpr size_t OFF_VB   = OFF_KB  + 16777216;
constexpr size_t OFF_TMPF = OFF_VB  + 16777216;        // 33554432 f32 tmp; later: [Cb 16MB | VbT 16MB]
constexpr size_t OFF_CB   = OFF_TMPF;
constexpr size_t OFF_VBT  = OFF_TMPF + 16777216;
constexpr size_t OFF_HSF  = OFF_TMPF + 33554432;       // 16777216
constexpr size_t OFF_CMX  = OFF_HSF + 16777216;        // 262144
constexpr size_t OFF_CSM  = OFF_CMX + 262144;          // 262144
constexpr size_t OFF_GMX  = OFF_CSM + 262144;          // 2048
constexpr size_t OFF_GSM  = OFF_GMX + 2048;
constexpr size_t OFF_PK   = OFF_GSM + 2048;            // 4194304
constexpr size_t OFF_PV   = OFF_PK  + 4194304;
constexpr size_t OFF_KCB  = OFF_PV  + 4194304;         // 65536
constexpr size_t OFF_VCT  = OFF_KCB + 65536;           // 65536

extern "C" void kernel_launch(void* const* d_in, const int* in_sizes, int n_in,
                              void* d_out, int out_size, void* d_ws, size_t ws_size,
                              hipStream_t stream)
{
  const float* X    = (const float*)d_in[0];
  const float* Wq   = (const float*)d_in[2];
  const float* Wqb  = (const float*)d_in[3];
  const float* Wk   = (const float*)d_in[4];
  const float* Wkb  = (const float*)d_in[5];
  const float* Wv   = (const float*)d_in[6];
  const float* Wvb  = (const float*)d_in[7];
  const float* Wo   = (const float*)d_in[8];
  const float* Wob  = (const float*)d_in[9];
  const float* lnlg = (const float*)d_in[10];
  const float* lnlb = (const float*)d_in[11];
  const float* lnsg = (const float*)d_in[12];
  const float* lnsb = (const float*)d_in[13];
  const float* Wd   = (const float*)d_in[14];
  const float* Wdb  = (const float*)d_in[15];
  float* out = (float*)d_out;

  char* ws = (char*)d_ws;
  u16*   Xb   = (u16*)(ws + OFF_XB);
  u16*   WqT  = (u16*)(ws + OFF_WQT);
  u16*   WkT  = (u16*)(ws + OFF_WKT);
  u16*   WvT  = (u16*)(ws + OFF_WVT);
  u16*   WoT  = (u16*)(ws + OFF_WOT);
  u16*   WdT  = (u16*)(ws + OFF_WDT);
  u16*   Qb   = (u16*)(ws + OFF_QB);
  u16*   Kb   = (u16*)(ws + OFF_KB);
  u16*   Vb   = (u16*)(ws + OFF_VB);
  float* tmpf = (float*)(ws + OFF_TMPF);
  u16*   Cbp  = (u16*)(ws + OFF_CB);
  u16*   VbT  = (u16*)(ws + OFF_VBT);
  float* hsf  = (float*)(ws + OFF_HSF);
  float* cmx  = (float*)(ws + OFF_CMX);
  float* csm  = (float*)(ws + OFF_CSM);
  float* gmx  = (float*)(ws + OFF_GMX);
  float* gsm  = (float*)(ws + OFF_GSM);
  float* pK   = (float*)(ws + OFF_PK);
  float* pV   = (float*)(ws + OFF_PV);
  u16*   Kcb  = (u16*)(ws + OFF_KCB);
  u16*   VcT  = (u16*)(ws + OFF_VCT);

  const float SCALE = 0.125f;

  cvt_x_kernel<<<dim3(4096), dim3(256), 0, stream>>>(X, Xb);
  transpose_w<<<dim3(16,16), dim3(256), 0, stream>>>(Wq, WqT, 512);
  transpose_w<<<dim3(16,16), dim3(256), 0, stream>>>(Wk, WkT, 512);
  transpose_w<<<dim3(16,16), dim3(256), 0, stream>>>(Wv, WvT, 512);
  transpose_w<<<dim3(16,16), dim3(256), 0, stream>>>(Wo, WoT, 512);
  transpose_w<<<dim3(8,16),  dim3(256), 0, stream>>>(Wd, WdT, 256);

  gemm_bt<1><<<dim3(4,128), dim3(256), 0, stream>>>(Xb, WqT, Wqb, nullptr, Qb, 512, SCALE);
  gemm_bt<0><<<dim3(4,128), dim3(256), 0, stream>>>(Xb, WkT, Wkb, tmpf, nullptr, 512, 1.f);
  ln_rows<<<dim3(4096), dim3(256), 0, stream>>>(tmpf, lnlg, lnlb, Kb);
  gemm_bt<0><<<dim3(4,128), dim3(256), 0, stream>>>(Xb, WvT, Wvb, tmpf, nullptr, 512, 1.f);
  ln_rows<<<dim3(4096), dim3(256), 0, stream>>>(tmpf, lnlg, lnlb, Vb);
  transpose_v<<<dim3(128,16), dim3(256), 0, stream>>>(Vb, VbT);
  gemm_bt<0><<<dim3(2,128), dim3(256), 0, stream>>>(Xb, WdT, Wdb, hsf, nullptr, 256, 1.f);

  smax_part<<<dim3(128,2), dim3(256), 0, stream>>>(hsf, cmx, csm);
  smax_comb<<<dim3(2), dim3(256), 0, stream>>>(cmx, csm, gmx, gsm);

  cmp_accum<<<dim3(32,16), dim3(256), 0, stream>>>(hsf, gmx, gsm, Kb, Vb, pK, pV);
  ln_c_kernel<<<dim3(64), dim3(256), 0, stream>>>(pK, pV, lnsg, lnsb, Kcb, VcT);

  attn2_kernel<<<dim3(64,8,2), dim3(512), 0, stream>>>(Qb, Kb, Kcb, VbT, VcT, Cbp);

  gemm_bt<0><<<dim3(4,128), dim3(256), 0, stream>>>(Cbp, WoT, Wob, out, nullptr, 512, 1.f);
}

// Round 3
// 198.491 us; speedup vs baseline: 1.2907x; 1.2014x over previous
//
#include <hip/hip_runtime.h>

typedef unsigned short u16;
typedef unsigned int u32;
typedef __attribute__((ext_vector_type(8))) short bf16x8;
typedef __attribute__((ext_vector_type(4))) float f32x4;

#define DEVI static __device__ __forceinline__

DEVI float bf2f(u16 u){ u32 x = ((u32)u) << 16; float f; __builtin_memcpy(&f, &x, 4); return f; }
DEVI u16 f2bf(float f){ u32 x; __builtin_memcpy(&x, &f, 4); u32 r = x + 0x7FFFu + ((x >> 16) & 1u); return (u16)(r >> 16); }
DEVI u32 pk2(float a, float b){ return ((u32)f2bf(b) << 16) | (u32)f2bf(a); }

DEVI f32x4 mfma16(bf16x8 a, bf16x8 b, f32x4 c){
  return __builtin_amdgcn_mfma_f32_16x16x32_bf16(a, b, c, 0, 0, 0);
}

typedef __attribute__((address_space(3))) u32* lds_ptr_t;
typedef const __attribute__((address_space(1))) u32* gbl_ptr_t;
DEVI void gload16(const void* g, const void* l){
  __builtin_amdgcn_global_load_lds((gbl_ptr_t)(unsigned long long)g,
                                   (lds_ptr_t)(unsigned long long)l,
                                   16, 0, 0);
}

// ---------------- X -> bf16 ----------------
__global__ void cvt_x_kernel(const float* __restrict__ X, u16* __restrict__ Xb){
  int i = blockIdx.x * 256 + threadIdx.x;
  const f32x4* p = (const f32x4*)X;
  f32x4 a = p[(size_t)i*2], c = p[(size_t)i*2 + 1];
  bf16x8 v;
  v[0]=(short)f2bf(a[0]); v[1]=(short)f2bf(a[1]); v[2]=(short)f2bf(a[2]); v[3]=(short)f2bf(a[3]);
  v[4]=(short)f2bf(c[0]); v[5]=(short)f2bf(c[1]); v[6]=(short)f2bf(c[2]); v[7]=(short)f2bf(c[3]);
  *(bf16x8*)(Xb + (size_t)i*8) = v;
}

// ---------------- all weight transposes + bias concat in ONE launch ----------------
// WT rows: [0,512) Wq^T, [512,1024) Wk^T, [1024,1536) Wv^T, [1536,1792) Wd^T, [1792,2304) Wo^T
__global__ void transpose_all(const float* __restrict__ Wq, const float* __restrict__ Wk,
                              const float* __restrict__ Wv, const float* __restrict__ Wd,
                              const float* __restrict__ Wo,
                              const float* __restrict__ Wqb, const float* __restrict__ Wkb,
                              const float* __restrict__ Wvb, const float* __restrict__ Wdb,
                              u16* __restrict__ WT, float* __restrict__ biasAll)
{
  int id = blockIdx.x;
  if (id >= 1152){
    int c = (id - 1152) * 256 + threadIdx.x;       // 0..1791
    float v = (c < 512) ? Wqb[c] : (c < 1024) ? Wkb[c-512] : (c < 1536) ? Wvb[c-1024] : Wdb[c-1536];
    biasAll[c] = v;
    return;
  }
  const float* W; int RO, N, local;
  if      (id < 256){ W = Wq; RO = 0;    N = 512; local = id; }
  else if (id < 512){ W = Wk; RO = 512;  N = 512; local = id - 256; }
  else if (id < 768){ W = Wv; RO = 1024; N = 512; local = id - 512; }
  else if (id < 896){ W = Wd; RO = 1536; N = 256; local = id - 768; }
  else              { W = Wo; RO = 1792; N = 512; local = id - 896; }
  int ntiles = N >> 5;
  int n0 = (local & (ntiles - 1)) * 32, k0 = (local / ntiles) * 32;
  __shared__ float tile[32][33];
  int tx = threadIdx.x & 31, ty = threadIdx.x >> 5;
  #pragma unroll
  for (int i = 0; i < 32; i += 8)
    tile[ty + i][tx] = W[(size_t)(k0 + ty + i) * N + n0 + tx];
  __syncthreads();
  #pragma unroll
  for (int i = 0; i < 32; i += 8)
    WT[(size_t)(RO + n0 + ty + i) * 512 + k0 + tx] = f2bf(tile[tx][ty + i]);
}

// ---------------- fused QKV+hs projection GEMM ----------------
// grid (14, 128): bx 0-3 -> Q, 4-7 -> K(preLN), 8-11 -> V(preLN), 12-13 -> hs (+col-softmax partials)
__global__ __launch_bounds__(256) void gemm_qkvh(
    const u16* __restrict__ Xb, const u16* __restrict__ WT, const float* __restrict__ biasAll,
    u16* __restrict__ Qb, u16* __restrict__ Kb, u16* __restrict__ Vb,
    float* __restrict__ hsf, float* __restrict__ cmx, float* __restrict__ csm)
{
  __shared__ __align__(16) u16 As[128*32];
  __shared__ __align__(16) u16 Bs[128*32];
  __shared__ float pm[2][128], ps[2][128];
  const int t = threadIdx.x, lane = t & 63, w = t >> 6;
  const int m0 = blockIdx.y * 128, n0 = blockIdx.x * 128;
  const int wr = (w >> 1) * 64, wc = (w & 1) * 64;
  const int lrow = lane & 15, lk = lane >> 4;
  const f32x4 fz = {0.f, 0.f, 0.f, 0.f};
  f32x4 acc[4][4];
  #pragma unroll
  for (int mi = 0; mi < 4; mi++)
    #pragma unroll
    for (int ni = 0; ni < 4; ni++) acc[mi][ni] = fz;

  for (int k0 = 0; k0 < 512; k0 += 32){
    #pragma unroll
    for (int r = 0; r < 2; r++){
      int idx = r*256 + t;
      int row = idx >> 2;
      int kc  = (idx & 3) ^ (row & 3);
      gload16(Xb + (size_t)(m0+row)*512 + k0 + kc*8, (const void*)(As + r*2048 + w*512));
      gload16(WT + (size_t)(n0+row)*512 + k0 + kc*8, (const void*)(Bs + r*2048 + w*512));
    }
    __syncthreads();
    bf16x8 af[4], bfv[4];
    #pragma unroll
    for (int i = 0; i < 4; i++){
      int ra = wr + i*16 + lrow;
      af[i]  = *(const bf16x8*)(As + ra*32 + ((lk ^ (ra & 3)) * 8));
      int rb = wc + i*16 + lrow;
      bfv[i] = *(const bf16x8*)(Bs + rb*32 + ((lk ^ (rb & 3)) * 8));
    }
    #pragma unroll
    for (int mi = 0; mi < 4; mi++)
      #pragma unroll
      for (int ni = 0; ni < 4; ni++)
        acc[mi][ni] = mfma16(af[mi], bfv[ni], acc[mi][ni]);
    __syncthreads();
  }

  const int sel = blockIdx.x >> 2;     // 0 Q, 1 K, 2 V, 3 hs
  if (sel < 3){
    u16* dst = (sel == 0) ? Qb : (sel == 1) ? Kb : Vb;
    const float scale = (sel == 0) ? 0.125f : 1.0f;
    #pragma unroll
    for (int mi = 0; mi < 4; mi++){
      #pragma unroll
      for (int ni = 0; ni < 4; ni++){
        int gcol = n0 + wc + ni*16 + lrow;
        int lcol = gcol & 511;
        float bv = biasAll[gcol];
        int hh = lcol >> 6, d = lcol & 63;
        #pragma unroll
        for (int r = 0; r < 4; r++){
          int grow = m0 + wr + mi*16 + lk*4 + r;
          int b = grow >> 13, s = grow & 8191;
          float v = (acc[mi][ni][r] + bv) * scale;
          dst[(((size_t)(b*8 + hh))*8192 + s)*64 + d] = f2bf(v);
        }
      }
    }
  } else {
    // hs: write hsf f32 and per-128-row column softmax partials
    float mx[4], sm[4];
    #pragma unroll
    for (int ni = 0; ni < 4; ni++){ mx[ni] = -1e30f; sm[ni] = 0.f; }
    #pragma unroll
    for (int ni = 0; ni < 4; ni++){
      int gcol = n0 + wc + ni*16 + lrow;
      float bv = biasAll[gcol];
      int c = gcol - 1536;
      #pragma unroll
      for (int mi = 0; mi < 4; mi++){
        #pragma unroll
        for (int r = 0; r < 4; r++){
          int grow = m0 + wr + mi*16 + lk*4 + r;
          float v = acc[mi][ni][r] + bv;
          hsf[(size_t)grow*256 + c] = v;
          float nm = fmaxf(mx[ni], v);
          sm[ni] = sm[ni]*__expf(mx[ni]-nm) + __expf(v-nm);
          mx[ni] = nm;
        }
      }
    }
    // combine across lk (lanes xor 16,32 share the same column)
    #pragma unroll
    for (int ni = 0; ni < 4; ni++){
      #pragma unroll
      for (int d2 = 16; d2 <= 32; d2 <<= 1){
        float om = __shfl_xor(mx[ni], d2);
        float os = __shfl_xor(sm[ni], d2);
        float nm = fmaxf(mx[ni], om);
        sm[ni] = sm[ni]*__expf(mx[ni]-nm) + os*__expf(om-nm);
        mx[ni] = nm;
      }
    }
    if (lk == 0){
      #pragma unroll
      for (int ni = 0; ni < 4; ni++){
        pm[wr >> 6][wc + ni*16 + lrow] = mx[ni];
        ps[wr >> 6][wc + ni*16 + lrow] = sm[ni];
      }
    }
    __syncthreads();
    if (t < 128){
      float ma = pm[0][t], mb = pm[1][t];
      float nm = fmaxf(ma, mb);
      float s = ps[0][t]*__expf(ma-nm) + ps[1][t]*__expf(mb-nm);
      int b = m0 >> 13, chunk = (m0 & 8191) >> 7;
      int c = (n0 - 1536) + t;
      cmx[((size_t)b*64 + chunk)*256 + c] = nm;
      csm[((size_t)b*64 + chunk)*256 + c] = s;
    }
  }
}

// ---------------- output GEMM: A[M][512]bf16 @ Bt[N][512]^T + bias -> f32 ----------------
__global__ __launch_bounds__(256) void gemm_out(
    const u16* __restrict__ A, const u16* __restrict__ Bt,
    const float* __restrict__ bias, float* __restrict__ Cf)
{
  __shared__ __align__(16) u16 As[128*32];
  __shared__ __align__(16) u16 Bs[128*32];
  const int t = threadIdx.x, lane = t & 63, w = t >> 6;
  const int m0 = blockIdx.y * 128, n0 = blockIdx.x * 128;
  const int wr = (w >> 1) * 64, wc = (w & 1) * 64;
  const int lrow = lane & 15, lk = lane >> 4;
  const f32x4 fz = {0.f, 0.f, 0.f, 0.f};
  f32x4 acc[4][4];
  #pragma unroll
  for (int mi = 0; mi < 4; mi++)
    #pragma unroll
    for (int ni = 0; ni < 4; ni++) acc[mi][ni] = fz;

  for (int k0 = 0; k0 < 512; k0 += 32){
    #pragma unroll
    for (int r = 0; r < 2; r++){
      int idx = r*256 + t;
      int row = idx >> 2;
      int kc  = (idx & 3) ^ (row & 3);
      gload16(A  + (size_t)(m0+row)*512 + k0 + kc*8, (const void*)(As + r*2048 + w*512));
      gload16(Bt + (size_t)(n0+row)*512 + k0 + kc*8, (const void*)(Bs + r*2048 + w*512));
    }
    __syncthreads();
    bf16x8 af[4], bfv[4];
    #pragma unroll
    for (int i = 0; i < 4; i++){
      int ra = wr + i*16 + lrow;
      af[i]  = *(const bf16x8*)(As + ra*32 + ((lk ^ (ra & 3)) * 8));
      int rb = wc + i*16 + lrow;
      bfv[i] = *(const bf16x8*)(Bs + rb*32 + ((lk ^ (rb & 3)) * 8));
    }
    #pragma unroll
    for (int mi = 0; mi < 4; mi++)
      #pragma unroll
      for (int ni = 0; ni < 4; ni++)
        acc[mi][ni] = mfma16(af[mi], bfv[ni], acc[mi][ni]);
    __syncthreads();
  }

  #pragma unroll
  for (int mi = 0; mi < 4; mi++){
    #pragma unroll
    for (int ni = 0; ni < 4; ni++){
      int gcol = n0 + wc + ni*16 + lrow;
      float bv = bias[gcol];
      #pragma unroll
      for (int r = 0; r < 4; r++){
        int grow = m0 + wr + mi*16 + lk*4 + r;
        Cf[(size_t)grow * 512 + gcol] = acc[mi][ni][r] + bv;
      }
    }
  }
}

// ---------------- in-place row LayerNorm on bf16 head-layout buffers ----------------
__global__ __launch_bounds__(256) void ln_both(u16* __restrict__ Kb, u16* __restrict__ Vb,
    const float* __restrict__ gg, const float* __restrict__ bb)
{
  u16* buf = blockIdx.y ? Vb : Kb;
  const int lane = threadIdx.x & 63, w = threadIdx.x >> 6;
  const int row = blockIdx.x * 4 + w;
  const int b = row >> 13, si = row & 8191;
  const int hh = lane >> 3, d = (lane & 7) * 8;
  u16* p = buf + (((size_t)(b*8 + hh))*8192 + si)*64 + d;
  bf16x8 raw = *(const bf16x8*)p;
  float x[8];
  #pragma unroll
  for (int j = 0; j < 8; j++) x[j] = bf2f((u16)raw[j]);
  float s = 0.f, q = 0.f;
  #pragma unroll
  for (int j = 0; j < 8; j++){ s += x[j]; q += x[j]*x[j]; }
  #pragma unroll
  for (int d2 = 1; d2 < 64; d2 <<= 1){ s += __shfl_xor(s, d2); q += __shfl_xor(q, d2); }
  float mean = s * (1.f/512.f);
  float var  = q * (1.f/512.f) - mean*mean;
  float rstd = rsqrtf(var + 1e-5f);
  int c0 = lane * 8;
  bf16x8 o;
  #pragma unroll
  for (int j = 0; j < 8; j++)
    o[j] = (short)f2bf((x[j] - mean) * rstd * gg[c0+j] + bb[c0+j]);
  *(bf16x8*)p = o;
}

// ---------------- V transpose: Vb [bh][8192][64] -> VbT [bh][64][8192] ----------------
__global__ __launch_bounds__(256) void transpose_v(const u16* __restrict__ Vb, u16* __restrict__ VbT){
  __shared__ u16 tile[64][72];
  const int st = blockIdx.x, bh = blockIdx.y;
  const int t = threadIdx.x;
  {
    int row = t >> 2, cc = (t & 3) * 16;
    const u16* src = Vb + ((size_t)bh*8192 + st*64 + row)*64 + cc;
    *(bf16x8*)&tile[row][cc]     = *(const bf16x8*)src;
    *(bf16x8*)&tile[row][cc + 8] = *(const bf16x8*)(src + 8);
  }
  __syncthreads();
  {
    int d = t >> 2, sc4 = (t & 3) * 16;
    bf16x8 o0, o1;
    #pragma unroll
    for (int i = 0; i < 8; i++) o0[i] = (short)tile[sc4 + i][d];
    #pragma unroll
    for (int i = 0; i < 8; i++) o1[i] = (short)tile[sc4 + 8 + i][d];
    u16* dst = VbT + ((size_t)bh*64 + d)*8192 + st*64 + sc4;
    *(bf16x8*)dst       = o0;
    *(bf16x8*)(dst + 8) = o1;
  }
}

// ---------------- combine column-softmax partials ----------------
__global__ void smax_comb(const float* __restrict__ cmax, const float* __restrict__ csum,
                          float* __restrict__ gmax, float* __restrict__ gsum){
  int b = blockIdx.x, c = threadIdx.x;
  float m = -1e30f, s = 0.f;
  for (int ch = 0; ch < 64; ch++){
    float cm = cmax[((size_t)b*64 + ch)*256 + c];
    float cs = csum[((size_t)b*64 + ch)*256 + c];
    float nm = fmaxf(m, cm);
    s = s*__expf(m - nm) + cs*__expf(cm - nm);
    m = nm;
  }
  gmax[b*256 + c] = m; gsum[b*256 + c] = s;
}

// ---------------- compressed K_c/V_c partial sums (softmax-normalize fused) ----------------
__global__ __launch_bounds__(256) void cmp_accum(const float* __restrict__ hsf,
    const float* __restrict__ gmax, const float* __restrict__ gsum,
    const u16* __restrict__ Kb, const u16* __restrict__ Vb,
    float* __restrict__ pK, float* __restrict__ pV)
{
  __shared__ float Pls[64*36];
  __shared__ __align__(16) float Klf[64*68];
  __shared__ __align__(16) float Vlf[64*68];
  const int sch = blockIdx.x, bh = blockIdx.y;
  const int b = bh >> 3, h = bh & 7;
  const int t = threadIdx.x;
  const int l = t >> 3, d0 = (t & 7) * 8;
  const int c0 = (t & 3) * 8;
  float gm[8], gi[8];
  #pragma unroll
  for (int j = 0; j < 8; j++){
    int c = h*32 + c0 + j;
    gm[j] = gmax[b*256 + c];
    gi[j] = 1.0f / gsum[b*256 + c];
  }
  float aK[8], aV[8];
  #pragma unroll
  for (int j = 0; j < 8; j++){ aK[j] = 0.f; aV[j] = 0.f; }

  for (int sub = 0; sub < 4; sub++){
    int s0 = sch*256 + sub*64;
    {
      int row = t >> 2;
      const float* src = hsf + ((size_t)b*8192 + s0 + row)*256 + h*32 + c0;
      f32x4 x0 = *(const f32x4*)src, x1 = *(const f32x4*)(src + 4);
      #pragma unroll
      for (int j = 0; j < 4; j++){
        Pls[row*36 + c0 + j]     = __expf(x0[j] - gm[j])   * gi[j];
        Pls[row*36 + c0 + 4 + j] = __expf(x1[j] - gm[4+j]) * gi[4+j];
      }
    }
    {
      int row = t >> 2, e0 = (t & 3) * 16;
      const u16* ks = Kb + ((size_t)bh*8192 + s0 + row)*64 + e0;
      const u16* vs = Vb + ((size_t)bh*8192 + s0 + row)*64 + e0;
      bf16x8 k0 = *(const bf16x8*)ks, k1 = *(const bf16x8*)(ks + 8);
      bf16x8 v0 = *(const bf16x8*)vs, v1 = *(const bf16x8*)(vs + 8);
      #pragma unroll
      for (int j = 0; j < 8; j++){
        Klf[row*68 + e0 + j]     = bf2f((u16)k0[j]);
        Klf[row*68 + e0 + 8 + j] = bf2f((u16)k1[j]);
        Vlf[row*68 + e0 + j]     = bf2f((u16)v0[j]);
        Vlf[row*68 + e0 + 8 + j] = bf2f((u16)v1[j]);
      }
    }
    __syncthreads();
    #pragma unroll 2
    for (int si = 0; si < 64; si++){
      float p = Pls[si*36 + l];
      f32x4 ka = *(const f32x4*)&Klf[si*68 + d0];
      f32x4 kb = *(const f32x4*)&Klf[si*68 + d0 + 4];
      f32x4 va = *(const f32x4*)&Vlf[si*68 + d0];
      f32x4 vb = *(const f32x4*)&Vlf[si*68 + d0 + 4];
      #pragma unroll
      for (int j = 0; j < 4; j++){
        aK[j]   += p * ka[j];
        aK[4+j] += p * kb[j];
        aV[j]   += p * va[j];
        aV[4+j] += p * vb[j];
      }
    }
    __syncthreads();
  }
  size_t base = ((size_t)bh*32 + sch)*2048 + l*64 + d0;
  #pragma unroll
  for (int j = 0; j < 8; j++){ pK[base + j] = aK[j]; pV[base + j] = aV[j]; }
}

// ---------------- reduce partials + LN_s -> Kcb [bh][32][64], VcT [bh][64][32] ----------------
__global__ __launch_bounds__(256) void ln_c_kernel(const float* __restrict__ pK, const float* __restrict__ pV,
    const float* __restrict__ gg, const float* __restrict__ bb,
    u16* __restrict__ Kcb, u16* __restrict__ VcT)
{
  __shared__ float red[4][4];
  const int b = blockIdx.x >> 5, l = blockIdx.x & 31;
  const int t = threadIdx.x, lane = t & 63, w = t >> 6;
  float xk[2], xv[2];
  #pragma unroll
  for (int q2 = 0; q2 < 2; q2++){
    int c = t + q2*256;
    int hh = c >> 6, d = c & 63;
    float sk = 0.f, sv = 0.f;
    for (int ch = 0; ch < 32; ch++){
      size_t idx = (((size_t)(b*8 + hh)*32 + ch)*2048) + l*64 + d;
      sk += pK[idx]; sv += pV[idx];
    }
    xk[q2] = sk; xv[q2] = sv;
  }
  float s1 = xk[0]+xk[1], q1 = xk[0]*xk[0]+xk[1]*xk[1];
  float s2 = xv[0]+xv[1], q2s = xv[0]*xv[0]+xv[1]*xv[1];
  #pragma unroll
  for (int d2 = 1; d2 < 64; d2 <<= 1){
    s1 += __shfl_xor(s1, d2); q1 += __shfl_xor(q1, d2);
    s2 += __shfl_xor(s2, d2); q2s += __shfl_xor(q2s, d2);
  }
  if (lane == 0){ red[0][w]=s1; red[1][w]=q1; red[2][w]=s2; red[3][w]=q2s; }
  __syncthreads();
  s1 = red[0][0]+red[0][1]+red[0][2]+red[0][3];
  q1 = red[1][0]+red[1][1]+red[1][2]+red[1][3];
  s2 = red[2][0]+red[2][1]+red[2][2]+red[2][3];
  q2s = red[3][0]+red[3][1]+red[3][2]+red[3][3];
  float mk = s1*(1.f/512.f), vk = q1*(1.f/512.f) - mk*mk, rk = rsqrtf(vk + 1e-5f);
  float mv = s2*(1.f/512.f), vvv = q2s*(1.f/512.f) - mv*mv, rv = rsqrtf(vvv + 1e-5f);
  #pragma unroll
  for (int q2 = 0; q2 < 2; q2++){
    int c = t + q2*256;
    int hh = c >> 6, d = c & 63;
    Kcb[(((size_t)(b*8 + hh))*32 + l)*64 + d] = f2bf((xk[q2]-mk)*rk*gg[c] + bb[c]);
    VcT[(((size_t)(b*8 + hh))*64 + d)*32 + l] = f2bf((xv[q2]-mv)*rv*gg[c] + bb[c]);
  }
}

// ---------------- fused long-short attention per (b,h,g), swapped-operand form ----------------
__global__ __launch_bounds__(512, 4) void attn2_kernel(
    const u16* __restrict__ Qb, const u16* __restrict__ Kb, const u16* __restrict__ Kcb,
    const u16* __restrict__ VbT, const u16* __restrict__ VcT, u16* __restrict__ Cb)
{
  __shared__ __align__(16) char smem[74752];
  u16* Vt = (u16*)(smem + 36864);
  u16* Pl = (u16*)smem;

  const int g = blockIdx.x, h = blockIdx.y, b = blockIdx.z;
  const int bh = b*8 + h;
  const int t = threadIdx.x, lane = t & 63, w = t >> 6;
  const int lrow = lane & 15, lk = lane >> 4;
  const int s0 = g*128 - 64;
  const bf16x8 bz = {0,0,0,0,0,0,0,0};
  const f32x4 fz = {0.f,0.f,0.f,0.f};

  #pragma unroll
  for (int it = 0; it < 5; it++){
    int idx = it*512 + t;
    if (idx < 2304){
      int row = idx >> 3, kc = idx & 7;
      bf16x8 v = bz;
      if (row < 256){
        int sk = s0 + row;
        if (sk >= 0 && sk < 8192) v = *(const bf16x8*)(Kb + ((size_t)bh*8192 + sk)*64 + kc*8);
      } else {
        v = *(const bf16x8*)(Kcb + ((size_t)bh*32 + (row - 256))*64 + kc*8);
      }
      int off = row*128 + kc*16; off ^= (row & 7) << 4;
      *(bf16x8*)(smem + off) = v;
    }
  }
  #pragma unroll
  for (int it = 0; it < 4; it++){
    int idx = it*512 + t;
    int d = idx >> 5, cc = idx & 31;
    int sk = s0 + cc*8;
    bf16x8 v = bz;
    if (sk >= 0 && sk < 8192) v = *(const bf16x8*)(VbT + ((size_t)bh*64 + d)*8192 + sk);
    *(bf16x8*)(Vt + d*296 + cc*8) = v;
  }
  if (t < 256){
    int d = t >> 2, cc = t & 3;
    bf16x8 v = *(const bf16x8*)(VcT + ((size_t)bh*64 + d)*32 + cc*8);
    *(bf16x8*)(Vt + d*296 + 256 + cc*8) = v;
  }
  bf16x8 qf[2];
  #pragma unroll
  for (int ks = 0; ks < 2; ks++)
    qf[ks] = *(const bf16x8*)(Qb + ((size_t)bh*8192 + g*128 + w*16 + lrow)*64 + ks*32 + lk*8);

  __syncthreads();

  f32x4 sc[18];
  #pragma unroll
  for (int j = 0; j < 18; j++) sc[j] = fz;
  #pragma unroll
  for (int j = 0; j < 18; j++){
    int row = j*16 + lrow;
    #pragma unroll
    for (int ks = 0; ks < 2; ks++){
      int off = row*128 + ks*64 + lk*16; off ^= (row & 7) << 4;
      bf16x8 kf = *(const bf16x8*)(smem + off);
      sc[j] = mfma16(kf, qf[ks], sc[j]);
    }
  }

  #pragma unroll
  for (int j = 0; j < 16; j++){
    int sb = s0 + j*16 + lk*4;
    if (sb < 0 || sb >= 8192){
      sc[j][0] = -1e30f; sc[j][1] = -1e30f; sc[j][2] = -1e30f; sc[j][3] = -1e30f;
    }
  }

  float m = -1e30f;
  #pragma unroll
  for (int j = 0; j < 18; j++)
    m = fmaxf(m, fmaxf(fmaxf(sc[j][0], sc[j][1]), fmaxf(sc[j][2], sc[j][3])));
  m = fmaxf(m, __shfl_xor(m, 16));
  m = fmaxf(m, __shfl_xor(m, 32));
  float ssum = 0.f;
  #pragma unroll
  for (int j = 0; j < 18; j++){
    #pragma unroll
    for (int r = 0; r < 4; r++){
      float e = __expf(sc[j][r] - m);
      sc[j][r] = e; ssum += e;
    }
  }
  ssum += __shfl_xor(ssum, 16);
  ssum += __shfl_xor(ssum, 32);
  float inv = 1.0f / ssum;

  f32x4 ao[4];
  #pragma unroll
  for (int nj = 0; nj < 4; nj++) ao[nj] = fz;
  const int prow = w*16 + lrow;

  #pragma unroll
  for (int c = 0; c < 3; c++){
    __syncthreads();
    #pragma unroll
    for (int jj = 0; jj < 6; jj++){
      int j = c*6 + jj;
      u32* dst = (u32*)(Pl + prow*104 + jj*16 + lk*4);
      dst[0] = pk2(sc[j][0], sc[j][1]);
      dst[1] = pk2(sc[j][2], sc[j][3]);
    }
    __syncthreads();
    #pragma unroll
    for (int ksl = 0; ksl < 3; ksl++){
      bf16x8 pb = *(const bf16x8*)(Pl + prow*104 + ksl*32 + lk*8);
      #pragma unroll
      for (int nj = 0; nj < 4; nj++){
        bf16x8 av = *(const bf16x8*)(Vt + (nj*16 + lrow)*296 + c*96 + ksl*32 + lk*8);
        ao[nj] = mfma16(av, pb, ao[nj]);
      }
    }
  }

  const int qglob = g*128 + w*16 + lrow;
  #pragma unroll
  for (int nj = 0; nj < 4; nj++){
    u32* dst = (u32*)(Cb + ((size_t)b*8192 + qglob)*512 + h*64 + nj*16 + lk*4);
    dst[0] = pk2(ao[nj][0]*inv, ao[nj][1]*inv);
    dst[1] = pk2(ao[nj][2]*inv, ao[nj][3]*inv);
  }
}

// ---------------- workspace layout ----------------
constexpr size_t OFF_XB   = 0;                         // 16777216
constexpr size_t OFF_WT   = OFF_XB  + 16777216;        // 2304*512*2 = 2359296
constexpr size_t OFF_QB   = OFF_WT  + 2359296;         // 16777216
constexpr size_t OFF_KB   = OFF_QB  + 16777216;
constexpr size_t OFF_VB   = OFF_KB  + 16777216;
constexpr size_t OFF_CB   = OFF_VB  + 16777216;        // 16777216 (attn out bf16)
constexpr size_t OFF_VBT  = OFF_CB  + 16777216;        // 16777216
constexpr size_t OFF_HSF  = OFF_VBT + 16777216;        // 16777216
constexpr size_t OFF_CMX  = OFF_HSF + 16777216;        // 131072
constexpr size_t OFF_CSM  = OFF_CMX + 131072;          // 131072
constexpr size_t OFF_GMX  = OFF_CSM + 131072;          // 2048
constexpr size_t OFF_GSM  = OFF_GMX + 2048;
constexpr size_t OFF_PK   = OFF_GSM + 2048;            // 4194304
constexpr size_t OFF_PV   = OFF_PK  + 4194304;
constexpr size_t OFF_KCB  = OFF_PV  + 4194304;         // 65536
constexpr size_t OFF_VCT  = OFF_KCB + 65536;           // 65536
constexpr size_t OFF_BIAS = OFF_VCT + 65536;           // 7168

extern "C" void kernel_launch(void* const* d_in, const int* in_sizes, int n_in,
                              void* d_out, int out_size, void* d_ws, size_t ws_size,
                              hipStream_t stream)
{
  const float* X    = (const float*)d_in[0];
  const float* Wq   = (const float*)d_in[2];
  const float* Wqb  = (const float*)d_in[3];
  const float* Wk   = (const float*)d_in[4];
  const float* Wkb  = (const float*)d_in[5];
  const float* Wv   = (const float*)d_in[6];
  const float* Wvb  = (const float*)d_in[7];
  const float* Wo   = (const float*)d_in[8];
  const float* Wob  = (const float*)d_in[9];
  const float* lnlg = (const float*)d_in[10];
  const float* lnlb = (const float*)d_in[11];
  const float* lnsg = (const float*)d_in[12];
  const float* lnsb = (const float*)d_in[13];
  const float* Wd   = (const float*)d_in[14];
  const float* Wdb  = (const float*)d_in[15];
  float* out = (float*)d_out;

  char* ws = (char*)d_ws;
  u16*   Xb   = (u16*)(ws + OFF_XB);
  u16*   WT   = (u16*)(ws + OFF_WT);
  u16*   Qb   = (u16*)(ws + OFF_QB);
  u16*   Kb   = (u16*)(ws + OFF_KB);
  u16*   Vb   = (u16*)(ws + OFF_VB);
  u16*   Cbp  = (u16*)(ws + OFF_CB);
  u16*   VbT  = (u16*)(ws + OFF_VBT);
  float* hsf  = (float*)(ws + OFF_HSF);
  float* cmx  = (float*)(ws + OFF_CMX);
  float* csm  = (float*)(ws + OFF_CSM);
  float* gmx  = (float*)(ws + OFF_GMX);
  float* gsm  = (float*)(ws + OFF_GSM);
  float* pK   = (float*)(ws + OFF_PK);
  float* pV   = (float*)(ws + OFF_PV);
  u16*   Kcb  = (u16*)(ws + OFF_KCB);
  u16*   VcT  = (u16*)(ws + OFF_VCT);
  float* biasAll = (float*)(ws + OFF_BIAS);

  cvt_x_kernel<<<dim3(4096), dim3(256), 0, stream>>>(X, Xb);
  transpose_all<<<dim3(1159), dim3(256), 0, stream>>>(Wq, Wk, Wv, Wd, Wo,
                                                      Wqb, Wkb, Wvb, Wdb, WT, biasAll);

  gemm_qkvh<<<dim3(14,128), dim3(256), 0, stream>>>(Xb, WT, biasAll, Qb, Kb, Vb, hsf, cmx, csm);

  ln_both<<<dim3(4096,2), dim3(256), 0, stream>>>(Kb, Vb, lnlg, lnlb);
  transpose_v<<<dim3(128,16), dim3(256), 0, stream>>>(Vb, VbT);

  smax_comb<<<dim3(2), dim3(256), 0, stream>>>(cmx, csm, gmx, gsm);

  cmp_accum<<<dim3(32,16), dim3(256), 0, stream>>>(hsf, gmx, gsm, Kb, Vb, pK, pV);
  ln_c_kernel<<<dim3(64), dim3(256), 0, stream>>>(pK, pV, lnsg, lnsb, Kcb, VcT);

  attn2_kernel<<<dim3(64,8,2), dim3(512), 0, stream>>>(Qb, Kb, Kcb, VbT, VcT, Cbp);

  gemm_out<<<dim3(4,128), dim3(256), 0, stream>>>(Cbp, WT + (size_t)1792*512, Wob, out);
}

// Round 4
// 176.761 us; speedup vs baseline: 1.4494x; 1.1229x over previous
//
#include <hip/hip_runtime.h>

typedef unsigned short u16;
typedef unsigned int u32;
typedef __attribute__((ext_vector_type(8))) short bf16x8;
typedef __attribute__((ext_vector_type(4))) float f32x4;

#define DEVI static __device__ __forceinline__

DEVI float bf2f(u16 u){ u32 x = ((u32)u) << 16; float f; __builtin_memcpy(&f, &x, 4); return f; }
DEVI u16 f2bf(float f){ u32 x; __builtin_memcpy(&x, &f, 4); u32 r = x + 0x7FFFu + ((x >> 16) & 1u); return (u16)(r >> 16); }
DEVI u32 pk2(float a, float b){ return ((u32)f2bf(b) << 16) | (u32)f2bf(a); }

DEVI f32x4 mfma16(bf16x8 a, bf16x8 b, f32x4 c){
  return __builtin_amdgcn_mfma_f32_16x16x32_bf16(a, b, c, 0, 0, 0);
}

typedef __attribute__((address_space(3))) u32* lds_ptr_t;
typedef const __attribute__((address_space(1))) u32* gbl_ptr_t;
DEVI void gload16(const void* g, const void* l){
  __builtin_amdgcn_global_load_lds((gbl_ptr_t)(unsigned long long)g,
                                   (lds_ptr_t)(unsigned long long)l,
                                   16, 0, 0);
}

// ---------------- X -> bf16 ----------------
__global__ void cvt_x_kernel(const float* __restrict__ X, u16* __restrict__ Xb){
  int i = blockIdx.x * 256 + threadIdx.x;
  const f32x4* p = (const f32x4*)X;
  f32x4 a = p[(size_t)i*2], c = p[(size_t)i*2 + 1];
  bf16x8 v;
  v[0]=(short)f2bf(a[0]); v[1]=(short)f2bf(a[1]); v[2]=(short)f2bf(a[2]); v[3]=(short)f2bf(a[3]);
  v[4]=(short)f2bf(c[0]); v[5]=(short)f2bf(c[1]); v[6]=(short)f2bf(c[2]); v[7]=(short)f2bf(c[3]);
  *(bf16x8*)(Xb + (size_t)i*8) = v;
}

// ---------------- all weight transposes + bias concat in ONE launch ----------------
// WT rows: [0,512) Wq^T, [512,1024) Wk^T, [1024,1536) Wv^T, [1536,1792) Wd^T, [1792,2304) Wo^T
__global__ void transpose_all(const float* __restrict__ Wq, const float* __restrict__ Wk,
                              const float* __restrict__ Wv, const float* __restrict__ Wd,
                              const float* __restrict__ Wo,
                              const float* __restrict__ Wqb, const float* __restrict__ Wkb,
                              const float* __restrict__ Wvb, const float* __restrict__ Wdb,
                              u16* __restrict__ WT, float* __restrict__ biasAll)
{
  int id = blockIdx.x;
  if (id >= 1152){
    int c = (id - 1152) * 256 + threadIdx.x;       // 0..1791
    float v = (c < 512) ? Wqb[c] : (c < 1024) ? Wkb[c-512] : (c < 1536) ? Wvb[c-1024] : Wdb[c-1536];
    biasAll[c] = v;
    return;
  }
  const float* W; int RO, N, local;
  if      (id < 256){ W = Wq; RO = 0;    N = 512; local = id; }
  else if (id < 512){ W = Wk; RO = 512;  N = 512; local = id - 256; }
  else if (id < 768){ W = Wv; RO = 1024; N = 512; local = id - 512; }
  else if (id < 896){ W = Wd; RO = 1536; N = 256; local = id - 768; }
  else              { W = Wo; RO = 1792; N = 512; local = id - 896; }
  int ntiles = N >> 5;
  int n0 = (local & (ntiles - 1)) * 32, k0 = (local / ntiles) * 32;
  __shared__ float tile[32][33];
  int tx = threadIdx.x & 31, ty = threadIdx.x >> 5;
  #pragma unroll
  for (int i = 0; i < 32; i += 8)
    tile[ty + i][tx] = W[(size_t)(k0 + ty + i) * N + n0 + tx];
  __syncthreads();
  #pragma unroll
  for (int i = 0; i < 32; i += 8)
    WT[(size_t)(RO + n0 + ty + i) * 512 + k0 + tx] = f2bf(tile[tx][ty + i]);
}

// ---------------- fused QKV+hs projection GEMM (XCD-remapped 1D grid of 1792) ----------------
// bx 0-3 -> Q, 4-7 -> K(preLN), 8-11 -> V(preLN + row stats), 12-13 -> hs (+col-softmax partials)
__global__ __launch_bounds__(256) void gemm_qkvh(
    const u16* __restrict__ Xb, const u16* __restrict__ WT, const float* __restrict__ biasAll,
    u16* __restrict__ Qb, u16* __restrict__ Kb, u16* __restrict__ Vb,
    float* __restrict__ hsf, float* __restrict__ cmx, float* __restrict__ csm,
    float* __restrict__ pstatV)
{
  __shared__ __align__(16) u16 As[128*32];
  __shared__ __align__(16) u16 Bs[128*32];
  __shared__ float pm[2][128], ps[2][128];
  __shared__ float vps[128][2], vqs[128][2];
  const int bid = blockIdx.x;
  const int xcd = bid & 7, cch = bid >> 3;          // 224 chunks per XCD
  const int by = xcd*16 + cch/14, bx = cch % 14;    // XCD owns contiguous m-range
  const int t = threadIdx.x, lane = t & 63, w = t >> 6;
  const int m0 = by * 128, n0 = bx * 128;
  const int wr = (w >> 1) * 64, wc = (w & 1) * 64;
  const int lrow = lane & 15, lk = lane >> 4;
  const f32x4 fz = {0.f, 0.f, 0.f, 0.f};
  f32x4 acc[4][4];
  #pragma unroll
  for (int mi = 0; mi < 4; mi++)
    #pragma unroll
    for (int ni = 0; ni < 4; ni++) acc[mi][ni] = fz;

  for (int k0 = 0; k0 < 512; k0 += 32){
    #pragma unroll
    for (int r = 0; r < 2; r++){
      int idx = r*256 + t;
      int row = idx >> 2;
      int kc  = (idx & 3) ^ (row & 3);
      gload16(Xb + (size_t)(m0+row)*512 + k0 + kc*8, (const void*)(As + r*2048 + w*512));
      gload16(WT + (size_t)(n0+row)*512 + k0 + kc*8, (const void*)(Bs + r*2048 + w*512));
    }
    __syncthreads();
    bf16x8 af[4], bfv[4];
    #pragma unroll
    for (int i = 0; i < 4; i++){
      int ra = wr + i*16 + lrow;
      af[i]  = *(const bf16x8*)(As + ra*32 + ((lk ^ (ra & 3)) * 8));
      int rb = wc + i*16 + lrow;
      bfv[i] = *(const bf16x8*)(Bs + rb*32 + ((lk ^ (rb & 3)) * 8));
    }
    #pragma unroll
    for (int mi = 0; mi < 4; mi++)
      #pragma unroll
      for (int ni = 0; ni < 4; ni++)
        acc[mi][ni] = mfma16(af[mi], bfv[ni], acc[mi][ni]);
    __syncthreads();
  }

  const int sel = bx >> 2;     // 0 Q, 1 K, 2 V, 3 hs
  if (sel < 3){
    u16* dst = (sel == 0) ? Qb : (sel == 1) ? Kb : Vb;
    const float scale = (sel == 0) ? 0.125f : 1.0f;
    #pragma unroll
    for (int mi = 0; mi < 4; mi++){
      #pragma unroll
      for (int ni = 0; ni < 4; ni++){
        int gcol = n0 + wc + ni*16 + lrow;
        int lcol = gcol & 511;
        float bv = biasAll[gcol];
        int hh = lcol >> 6, d = lcol & 63;
        #pragma unroll
        for (int r = 0; r < 4; r++){
          int grow = m0 + wr + mi*16 + lk*4 + r;
          int b = grow >> 13, s = grow & 8191;
          float v = (acc[mi][ni][r] + bv) * scale;
          dst[(((size_t)(b*8 + hh))*8192 + s)*64 + d] = f2bf(v);
        }
      }
    }
    if (sel == 2){
      // per-row partial sum/sumsq over this block's 128 cols (for V LayerNorm)
      float bvv[4];
      #pragma unroll
      for (int ni = 0; ni < 4; ni++) bvv[ni] = biasAll[n0 + wc + ni*16 + lrow];
      #pragma unroll
      for (int mi = 0; mi < 4; mi++){
        #pragma unroll
        for (int r = 0; r < 4; r++){
          float s = 0.f, q = 0.f;
          #pragma unroll
          for (int ni = 0; ni < 4; ni++){
            float v = acc[mi][ni][r] + bvv[ni];
            s += v; q += v*v;
          }
          #pragma unroll
          for (int d2 = 1; d2 < 16; d2 <<= 1){ s += __shfl_xor(s, d2); q += __shfl_xor(q, d2); }
          if (lrow == 0){
            int rloc = wr + mi*16 + lk*4 + r;
            vps[rloc][w & 1] = s; vqs[rloc][w & 1] = q;
          }
        }
      }
      __syncthreads();
      if (t < 128){
        float s = vps[t][0] + vps[t][1], q = vqs[t][0] + vqs[t][1];
        size_t o = (size_t)(m0 + t)*8 + (bx - 8)*2;
        pstatV[o] = s; pstatV[o + 1] = q;
      }
    }
  } else {
    float mx[4], sm[4];
    #pragma unroll
    for (int ni = 0; ni < 4; ni++){ mx[ni] = -1e30f; sm[ni] = 0.f; }
    #pragma unroll
    for (int ni = 0; ni < 4; ni++){
      int gcol = n0 + wc + ni*16 + lrow;
      float bv = biasAll[gcol];
      int c = gcol - 1536;
      #pragma unroll
      for (int mi = 0; mi < 4; mi++){
        #pragma unroll
        for (int r = 0; r < 4; r++){
          int grow = m0 + wr + mi*16 + lk*4 + r;
          float v = acc[mi][ni][r] + bv;
          hsf[(size_t)grow*256 + c] = v;
          float nm = fmaxf(mx[ni], v);
          sm[ni] = sm[ni]*__expf(mx[ni]-nm) + __expf(v-nm);
          mx[ni] = nm;
        }
      }
    }
    #pragma unroll
    for (int ni = 0; ni < 4; ni++){
      #pragma unroll
      for (int d2 = 16; d2 <= 32; d2 <<= 1){
        float om = __shfl_xor(mx[ni], d2);
        float os = __shfl_xor(sm[ni], d2);
        float nm = fmaxf(mx[ni], om);
        sm[ni] = sm[ni]*__expf(mx[ni]-nm) + os*__expf(om-nm);
        mx[ni] = nm;
      }
    }
    if (lk == 0){
      #pragma unroll
      for (int ni = 0; ni < 4; ni++){
        pm[wr >> 6][wc + ni*16 + lrow] = mx[ni];
        ps[wr >> 6][wc + ni*16 + lrow] = sm[ni];
      }
    }
    __syncthreads();
    if (t < 128){
      float ma = pm[0][t], mb = pm[1][t];
      float nm = fmaxf(ma, mb);
      float s = ps[0][t]*__expf(ma-nm) + ps[1][t]*__expf(mb-nm);
      int b = m0 >> 13, chunk = (m0 & 8191) >> 7;
      int c = (n0 - 1536) + t;
      cmx[((size_t)b*64 + chunk)*256 + c] = nm;
      csm[((size_t)b*64 + chunk)*256 + c] = s;
    }
  }
}

// ---------------- output GEMM (XCD-remapped 1D grid of 512) ----------------
__global__ __launch_bounds__(256) void gemm_out(
    const u16* __restrict__ A, const u16* __restrict__ Bt,
    const float* __restrict__ bias, float* __restrict__ Cf)
{
  __shared__ __align__(16) u16 As[128*32];
  __shared__ __align__(16) u16 Bs[128*32];
  const int bid = blockIdx.x;
  const int xcd = bid & 7, cch = bid >> 3;
  const int by = xcd*16 + (cch >> 2), bx = cch & 3;
  const int t = threadIdx.x, lane = t & 63, w = t >> 6;
  const int m0 = by * 128, n0 = bx * 128;
  const int wr = (w >> 1) * 64, wc = (w & 1) * 64;
  const int lrow = lane & 15, lk = lane >> 4;
  const f32x4 fz = {0.f, 0.f, 0.f, 0.f};
  f32x4 acc[4][4];
  #pragma unroll
  for (int mi = 0; mi < 4; mi++)
    #pragma unroll
    for (int ni = 0; ni < 4; ni++) acc[mi][ni] = fz;

  for (int k0 = 0; k0 < 512; k0 += 32){
    #pragma unroll
    for (int r = 0; r < 2; r++){
      int idx = r*256 + t;
      int row = idx >> 2;
      int kc  = (idx & 3) ^ (row & 3);
      gload16(A  + (size_t)(m0+row)*512 + k0 + kc*8, (const void*)(As + r*2048 + w*512));
      gload16(Bt + (size_t)(n0+row)*512 + k0 + kc*8, (const void*)(Bs + r*2048 + w*512));
    }
    __syncthreads();
    bf16x8 af[4], bfv[4];
    #pragma unroll
    for (int i = 0; i < 4; i++){
      int ra = wr + i*16 + lrow;
      af[i]  = *(const bf16x8*)(As + ra*32 + ((lk ^ (ra & 3)) * 8));
      int rb = wc + i*16 + lrow;
      bfv[i] = *(const bf16x8*)(Bs + rb*32 + ((lk ^ (rb & 3)) * 8));
    }
    #pragma unroll
    for (int mi = 0; mi < 4; mi++)
      #pragma unroll
      for (int ni = 0; ni < 4; ni++)
        acc[mi][ni] = mfma16(af[mi], bfv[ni], acc[mi][ni]);
    __syncthreads();
  }

  #pragma unroll
  for (int mi = 0; mi < 4; mi++){
    #pragma unroll
    for (int ni = 0; ni < 4; ni++){
      int gcol = n0 + wc + ni*16 + lrow;
      float bv = bias[gcol];
      #pragma unroll
      for (int r = 0; r < 4; r++){
        int grow = m0 + wr + mi*16 + lk*4 + r;
        Cf[(size_t)grow * 512 + gcol] = acc[mi][ni][r] + bv;
      }
    }
  }
}

// ---------------- in-place row LayerNorm on K (bf16 head layout) ----------------
__global__ __launch_bounds__(256) void ln_k(u16* __restrict__ Kb,
    const float* __restrict__ gg, const float* __restrict__ bb)
{
  const int lane = threadIdx.x & 63, w = threadIdx.x >> 6;
  const int row = blockIdx.x * 4 + w;
  const int b = row >> 13, si = row & 8191;
  const int hh = lane >> 3, d = (lane & 7) * 8;
  u16* p = Kb + (((size_t)(b*8 + hh))*8192 + si)*64 + d;
  bf16x8 raw = *(const bf16x8*)p;
  float x[8];
  #pragma unroll
  for (int j = 0; j < 8; j++) x[j] = bf2f((u16)raw[j]);
  float s = 0.f, q = 0.f;
  #pragma unroll
  for (int j = 0; j < 8; j++){ s += x[j]; q += x[j]*x[j]; }
  #pragma unroll
  for (int d2 = 1; d2 < 64; d2 <<= 1){ s += __shfl_xor(s, d2); q += __shfl_xor(q, d2); }
  float mean = s * (1.f/512.f);
  float var  = q * (1.f/512.f) - mean*mean;
  float rstd = rsqrtf(var + 1e-5f);
  int c0 = lane * 8;
  bf16x8 o;
  #pragma unroll
  for (int j = 0; j < 8; j++)
    o[j] = (short)f2bf((x[j] - mean) * rstd * gg[c0+j] + bb[c0+j]);
  *(bf16x8*)p = o;
}

// ---------------- V: LN (from gemm stats) + transpose -> VbT [bh][64][8192] ----------------
__global__ __launch_bounds__(256) void transpose_ln_v(const u16* __restrict__ Vb,
    const float* __restrict__ pstatV, const float* __restrict__ gg, const float* __restrict__ bb,
    u16* __restrict__ VbT)
{
  __shared__ u16 tile[64][72];
  const int st = blockIdx.x, bh = blockIdx.y;
  const int b = bh >> 3, h = bh & 7;
  const int t = threadIdx.x;
  {
    int row = t >> 2, cc = (t & 3) * 16;
    int grow = b*8192 + st*64 + row;
    f32x4 p0 = *(const f32x4*)(pstatV + (size_t)grow*8);
    f32x4 p1 = *(const f32x4*)(pstatV + (size_t)grow*8 + 4);
    float mean = (p0[0]+p0[2]+p1[0]+p1[2]) * (1.f/512.f);
    float msq  = (p0[1]+p0[3]+p1[1]+p1[3]) * (1.f/512.f);
    float rstd = rsqrtf(msq - mean*mean + 1e-5f);
    const u16* src = Vb + ((size_t)bh*8192 + st*64 + row)*64 + cc;
    bf16x8 v0 = *(const bf16x8*)src, v1 = *(const bf16x8*)(src + 8);
    #pragma unroll
    for (int j = 0; j < 8; j++){
      int c = h*64 + cc + j;
      tile[row][cc + j]     = f2bf((bf2f((u16)v0[j]) - mean)*rstd*gg[c] + bb[c]);
      int c2 = c + 8;
      tile[row][cc + 8 + j] = f2bf((bf2f((u16)v1[j]) - mean)*rstd*gg[c2] + bb[c2]);
    }
  }
  __syncthreads();
  {
    int d = t >> 2, sc4 = (t & 3) * 16;
    bf16x8 o0, o1;
    #pragma unroll
    for (int i = 0; i < 8; i++) o0[i] = (short)tile[sc4 + i][d];
    #pragma unroll
    for (int i = 0; i < 8; i++) o1[i] = (short)tile[sc4 + 8 + i][d];
    u16* dst = VbT + ((size_t)bh*64 + d)*8192 + st*64 + sc4;
    *(bf16x8*)dst       = o0;
    *(bf16x8*)(dst + 8) = o1;
  }
}

// ---------------- combine column-softmax partials (4 independent chains) ----------------
__global__ void smax_comb(const float* __restrict__ cmax, const float* __restrict__ csum,
                          float* __restrict__ gmax, float* __restrict__ gsum){
  int b = blockIdx.x, c = threadIdx.x;
  float m[4], s[4];
  #pragma unroll
  for (int u = 0; u < 4; u++){ m[u] = -1e30f; s[u] = 0.f; }
  for (int ch = 0; ch < 64; ch += 4){
    #pragma unroll
    for (int u = 0; u < 4; u++){
      float cm = cmax[((size_t)b*64 + ch + u)*256 + c];
      float cs = csum[((size_t)b*64 + ch + u)*256 + c];
      float nm = fmaxf(m[u], cm);
      s[u] = s[u]*__expf(m[u] - nm) + cs*__expf(cm - nm);
      m[u] = nm;
    }
  }
  #pragma unroll
  for (int u = 1; u < 4; u++){
    float nm = fmaxf(m[0], m[u]);
    s[0] = s[0]*__expf(m[0]-nm) + s[u]*__expf(m[u]-nm);
    m[0] = nm;
  }
  gmax[b*256 + c] = m[0]; gsum[b*256 + c] = s[0];
}

// ---------------- compressed K_c/V_c partial sums via MFMA ----------------
// grid (32 sch, 16 bh), 256 thr. Contraction over s: P^T[32][s] @ {K,V}[s][64].
__global__ __launch_bounds__(256) void cmp2_kernel(const float* __restrict__ hsf,
    const float* __restrict__ gmax, const float* __restrict__ gsum,
    const u16* __restrict__ Kb, const u16* __restrict__ Vb,
    const float* __restrict__ pstatV, const float* __restrict__ gg, const float* __restrict__ bb,
    float* __restrict__ pK, float* __restrict__ pV)
{
  __shared__ __align__(16) u16 Pt[32*72];   // [l][s] stride 72
  __shared__ __align__(16) u16 Kt[64*72];   // [d][s]
  __shared__ __align__(16) u16 Vt[64*72];   // [d][s] (normalized)
  const int sch = blockIdx.x, bh = blockIdx.y;
  const int b = bh >> 3, h = bh & 7;
  const int t = threadIdx.x, lane = t & 63, w = t >> 6;
  const int lrow = lane & 15, lk = lane >> 4;
  const int sl = lane;                      // staging s index within tile
  float gm[8], gi[8];
  #pragma unroll
  for (int j = 0; j < 8; j++){
    int c = h*32 + w*8 + j;
    gm[j] = gmax[b*256 + c];
    gi[j] = 1.0f / gsum[b*256 + c];
  }
  float glv[16], blv[16];
  #pragma unroll
  for (int j = 0; j < 16; j++){
    int c = h*64 + w*16 + j;
    glv[j] = gg[c]; blv[j] = bb[c];
  }
  const f32x4 fz = {0.f,0.f,0.f,0.f};
  f32x4 aK[2], aV[2];
  aK[0]=fz; aK[1]=fz; aV[0]=fz; aV[1]=fz;

  for (int tile = 0; tile < 4; ++tile){
    int s0 = sch*256 + tile*64;
    int grow = b*8192 + s0 + sl;
    {// P^T staging: this warp covers l = w*8 .. w*8+7, col s = sl
      const float* src = hsf + (size_t)grow*256 + h*32 + w*8;
      f32x4 x0 = *(const f32x4*)src, x1 = *(const f32x4*)(src + 4);
      #pragma unroll
      for (int j = 0; j < 4; j++){
        Pt[(w*8 + j)*72 + sl]     = f2bf(__expf(x0[j] - gm[j])   * gi[j]);
        Pt[(w*8 + 4 + j)*72 + sl] = f2bf(__expf(x1[j] - gm[4+j]) * gi[4+j]);
      }
    }
    {// K staging (already normalized): warp covers d = w*16 .. +15
      const u16* ks = Kb + ((size_t)bh*8192 + s0 + sl)*64 + w*16;
      bf16x8 k0 = *(const bf16x8*)ks, k1 = *(const bf16x8*)(ks + 8);
      #pragma unroll
      for (int j = 0; j < 8; j++){
        Kt[(w*16 + j)*72 + sl]     = (u16)k0[j];
        Kt[(w*16 + 8 + j)*72 + sl] = (u16)k1[j];
      }
    }
    {// V staging with on-the-fly LayerNorm from gemm partials
      f32x4 p0 = *(const f32x4*)(pstatV + (size_t)grow*8);
      f32x4 p1 = *(const f32x4*)(pstatV + (size_t)grow*8 + 4);
      float mean = (p0[0]+p0[2]+p1[0]+p1[2]) * (1.f/512.f);
      float msq  = (p0[1]+p0[3]+p1[1]+p1[3]) * (1.f/512.f);
      float rstd = rsqrtf(msq - mean*mean + 1e-5f);
      const u16* vs = Vb + ((size_t)bh*8192 + s0 + sl)*64 + w*16;
      bf16x8 v0 = *(const bf16x8*)vs, v1 = *(const bf16x8*)(vs + 8);
      #pragma unroll
      for (int j = 0; j < 8; j++){
        Vt[(w*16 + j)*72 + sl]     = f2bf((bf2f((u16)v0[j]) - mean)*rstd*glv[j]   + blv[j]);
        Vt[(w*16 + 8 + j)*72 + sl] = f2bf((bf2f((u16)v1[j]) - mean)*rstd*glv[8+j] + blv[8+j]);
      }
    }
    __syncthreads();
    #pragma unroll
    for (int ks = 0; ks < 2; ks++){
      bf16x8 a0 = *(const bf16x8*)(Pt + (lrow)*72      + ks*32 + lk*8);
      bf16x8 a1 = *(const bf16x8*)(Pt + (16 + lrow)*72 + ks*32 + lk*8);
      bf16x8 bK = *(const bf16x8*)(Kt + (w*16 + lrow)*72 + ks*32 + lk*8);
      bf16x8 bV = *(const bf16x8*)(Vt + (w*16 + lrow)*72 + ks*32 + lk*8);
      aK[0] = mfma16(a0, bK, aK[0]);
      aK[1] = mfma16(a1, bK, aK[1]);
      aV[0] = mfma16(a0, bV, aV[0]);
      aV[1] = mfma16(a1, bV, aV[1]);
    }
    __syncthreads();
  }
  // C[l][d]: l = li*16 + lk*4 + r, d = w*16 + lrow
  size_t base = ((size_t)bh*32 + sch)*2048;
  #pragma unroll
  for (int li = 0; li < 2; li++){
    #pragma unroll
    for (int r = 0; r < 4; r++){
      size_t o = base + (size_t)(li*16 + lk*4 + r)*64 + w*16 + lrow;
      pK[o] = aK[li][r];
      pV[o] = aV[li][r];
    }
  }
}

// ---------------- reduce partials + LN_s -> Kcb [bh][32][64], VcT [bh][64][32] ----------------
__global__ __launch_bounds__(256) void ln_c_kernel(const float* __restrict__ pK, const float* __restrict__ pV,
    const float* __restrict__ gg, const float* __restrict__ bb,
    u16* __restrict__ Kcb, u16* __restrict__ VcT)
{
  __shared__ float red[4][4];
  const int b = blockIdx.x >> 5, l = blockIdx.x & 31;
  const int t = threadIdx.x, lane = t & 63, w = t >> 6;
  float xk[2], xv[2];
  #pragma unroll
  for (int q2 = 0; q2 < 2; q2++){
    int c = t + q2*256;
    int hh = c >> 6, d = c & 63;
    float sk = 0.f, sv = 0.f;
    for (int ch = 0; ch < 32; ch++){
      size_t idx = (((size_t)(b*8 + hh)*32 + ch)*2048) + l*64 + d;
      sk += pK[idx]; sv += pV[idx];
    }
    xk[q2] = sk; xv[q2] = sv;
  }
  float s1 = xk[0]+xk[1], q1 = xk[0]*xk[0]+xk[1]*xk[1];
  float s2 = xv[0]+xv[1], q2s = xv[0]*xv[0]+xv[1]*xv[1];
  #pragma unroll
  for (int d2 = 1; d2 < 64; d2 <<= 1){
    s1 += __shfl_xor(s1, d2); q1 += __shfl_xor(q1, d2);
    s2 += __shfl_xor(s2, d2); q2s += __shfl_xor(q2s, d2);
  }
  if (lane == 0){ red[0][w]=s1; red[1][w]=q1; red[2][w]=s2; red[3][w]=q2s; }
  __syncthreads();
  s1 = red[0][0]+red[0][1]+red[0][2]+red[0][3];
  q1 = red[1][0]+red[1][1]+red[1][2]+red[1][3];
  s2 = red[2][0]+red[2][1]+red[2][2]+red[2][3];
  q2s = red[3][0]+red[3][1]+red[3][2]+red[3][3];
  float mk = s1*(1.f/512.f), vk = q1*(1.f/512.f) - mk*mk, rk = rsqrtf(vk + 1e-5f);
  float mv = s2*(1.f/512.f), vvv = q2s*(1.f/512.f) - mv*mv, rv = rsqrtf(vvv + 1e-5f);
  #pragma unroll
  for (int q2 = 0; q2 < 2; q2++){
    int c = t + q2*256;
    int hh = c >> 6, d = c & 63;
    Kcb[(((size_t)(b*8 + hh))*32 + l)*64 + d] = f2bf((xk[q2]-mk)*rk*gg[c] + bb[c]);
    VcT[(((size_t)(b*8 + hh))*64 + d)*32 + l] = f2bf((xv[q2]-mv)*rv*gg[c] + bb[c]);
  }
}

// ---------------- fused long-short attention per (b,h,g), swapped-operand form ----------------
__global__ __launch_bounds__(512, 4) void attn2_kernel(
    const u16* __restrict__ Qb, const u16* __restrict__ Kb, const u16* __restrict__ Kcb,
    const u16* __restrict__ VbT, const u16* __restrict__ VcT, u16* __restrict__ Cb)
{
  __shared__ __align__(16) char smem[74752];
  u16* Vt = (u16*)(smem + 36864);
  u16* Pl = (u16*)smem;

  const int g = blockIdx.x, h = blockIdx.y, b = blockIdx.z;
  const int bh = b*8 + h;
  const int t = threadIdx.x, lane = t & 63, w = t >> 6;
  const int lrow = lane & 15, lk = lane >> 4;
  const int s0 = g*128 - 64;
  const bf16x8 bz = {0,0,0,0,0,0,0,0};
  const f32x4 fz = {0.f,0.f,0.f,0.f};

  #pragma unroll
  for (int it = 0; it < 5; it++){
    int idx = it*512 + t;
    if (idx < 2304){
      int row = idx >> 3, kc = idx & 7;
      bf16x8 v = bz;
      if (row < 256){
        int sk = s0 + row;
        if (sk >= 0 && sk < 8192) v = *(const bf16x8*)(Kb + ((size_t)bh*8192 + sk)*64 + kc*8);
      } else {
        v = *(const bf16x8*)(Kcb + ((size_t)bh*32 + (row - 256))*64 + kc*8);
      }
      int off = row*128 + kc*16; off ^= (row & 7) << 4;
      *(bf16x8*)(smem + off) = v;
    }
  }
  #pragma unroll
  for (int it = 0; it < 4; it++){
    int idx = it*512 + t;
    int d = idx >> 5, cc = idx & 31;
    int sk = s0 + cc*8;
    bf16x8 v = bz;
    if (sk >= 0 && sk < 8192) v = *(const bf16x8*)(VbT + ((size_t)bh*64 + d)*8192 + sk);
    *(bf16x8*)(Vt + d*296 + cc*8) = v;
  }
  if (t < 256){
    int d = t >> 2, cc = t & 3;
    bf16x8 v = *(const bf16x8*)(VcT + ((size_t)bh*64 + d)*32 + cc*8);
    *(bf16x8*)(Vt + d*296 + 256 + cc*8) = v;
  }
  bf16x8 qf[2];
  #pragma unroll
  for (int ks = 0; ks < 2; ks++)
    qf[ks] = *(const bf16x8*)(Qb + ((size_t)bh*8192 + g*128 + w*16 + lrow)*64 + ks*32 + lk*8);

  __syncthreads();

  f32x4 sc[18];
  #pragma unroll
  for (int j = 0; j < 18; j++) sc[j] = fz;
  #pragma unroll
  for (int j = 0; j < 18; j++){
    int row = j*16 + lrow;
    #pragma unroll
    for (int ks = 0; ks < 2; ks++){
      int off = row*128 + ks*64 + lk*16; off ^= (row & 7) << 4;
      bf16x8 kf = *(const bf16x8*)(smem + off);
      sc[j] = mfma16(kf, qf[ks], sc[j]);
    }
  }

  #pragma unroll
  for (int j = 0; j < 16; j++){
    int sb = s0 + j*16 + lk*4;
    if (sb < 0 || sb >= 8192){
      sc[j][0] = -1e30f; sc[j][1] = -1e30f; sc[j][2] = -1e30f; sc[j][3] = -1e30f;
    }
  }

  float m = -1e30f;
  #pragma unroll
  for (int j = 0; j < 18; j++)
    m = fmaxf(m, fmaxf(fmaxf(sc[j][0], sc[j][1]), fmaxf(sc[j][2], sc[j][3])));
  m = fmaxf(m, __shfl_xor(m, 16));
  m = fmaxf(m, __shfl_xor(m, 32));
  float ssum = 0.f;
  #pragma unroll
  for (int j = 0; j < 18; j++){
    #pragma unroll
    for (int r = 0; r < 4; r++){
      float e = __expf(sc[j][r] - m);
      sc[j][r] = e; ssum += e;
    }
  }
  ssum += __shfl_xor(ssum, 16);
  ssum += __shfl_xor(ssum, 32);
  float inv = 1.0f / ssum;

  f32x4 ao[4];
  #pragma unroll
  for (int nj = 0; nj < 4; nj++) ao[nj] = fz;
  const int prow = w*16 + lrow;

  #pragma unroll
  for (int c = 0; c < 3; c++){
    __syncthreads();
    #pragma unroll
    for (int jj = 0; jj < 6; jj++){
      int j = c*6 + jj;
      u32* dst = (u32*)(Pl + prow*104 + jj*16 + lk*4);
      dst[0] = pk2(sc[j][0], sc[j][1]);
      dst[1] = pk2(sc[j][2], sc[j][3]);
    }
    __syncthreads();
    #pragma unroll
    for (int ksl = 0; ksl < 3; ksl++){
      bf16x8 pb = *(const bf16x8*)(Pl + prow*104 + ksl*32 + lk*8);
      #pragma unroll
      for (int nj = 0; nj < 4; nj++){
        bf16x8 av = *(const bf16x8*)(Vt + (nj*16 + lrow)*296 + c*96 + ksl*32 + lk*8);
        ao[nj] = mfma16(av, pb, ao[nj]);
      }
    }
  }

  const int qglob = g*128 + w*16 + lrow;
  #pragma unroll
  for (int nj = 0; nj < 4; nj++){
    u32* dst = (u32*)(Cb + ((size_t)b*8192 + qglob)*512 + h*64 + nj*16 + lk*4);
    dst[0] = pk2(ao[nj][0]*inv, ao[nj][1]*inv);
    dst[1] = pk2(ao[nj][2]*inv, ao[nj][3]*inv);
  }
}

// ---------------- workspace layout ----------------
constexpr size_t OFF_XB   = 0;
constexpr size_t OFF_WT   = OFF_XB  + 16777216;
constexpr size_t OFF_QB   = OFF_WT  + 2359296;
constexpr size_t OFF_KB   = OFF_QB  + 16777216;
constexpr size_t OFF_VB   = OFF_KB  + 16777216;
constexpr size_t OFF_CB   = OFF_VB  + 16777216;
constexpr size_t OFF_VBT  = OFF_CB  + 16777216;
constexpr size_t OFF_HSF  = OFF_VBT + 16777216;
constexpr size_t OFF_CMX  = OFF_HSF + 16777216;
constexpr size_t OFF_CSM  = OFF_CMX + 131072;
constexpr size_t OFF_GMX  = OFF_CSM + 131072;
constexpr size_t OFF_GSM  = OFF_GMX + 2048;
constexpr size_t OFF_PK   = OFF_GSM + 2048;
constexpr size_t OFF_PV   = OFF_PK  + 4194304;
constexpr size_t OFF_KCB  = OFF_PV  + 4194304;
constexpr size_t OFF_VCT  = OFF_KCB + 65536;
constexpr size_t OFF_BIAS = OFF_VCT + 65536;
constexpr size_t OFF_PSV  = OFF_BIAS + 8192;          // 16384*8*4 = 524288

extern "C" void kernel_launch(void* const* d_in, const int* in_sizes, int n_in,
                              void* d_out, int out_size, void* d_ws, size_t ws_size,
                              hipStream_t stream)
{
  const float* X    = (const float*)d_in[0];
  const float* Wq   = (const float*)d_in[2];
  const float* Wqb  = (const float*)d_in[3];
  const float* Wk   = (const float*)d_in[4];
  const float* Wkb  = (const float*)d_in[5];
  const float* Wv   = (const float*)d_in[6];
  const float* Wvb  = (const float*)d_in[7];
  const float* Wo   = (const float*)d_in[8];
  const float* Wob  = (const float*)d_in[9];
  const float* lnlg = (const float*)d_in[10];
  const float* lnlb = (const float*)d_in[11];
  const float* lnsg = (const float*)d_in[12];
  const float* lnsb = (const float*)d_in[13];
  const float* Wd   = (const float*)d_in[14];
  const float* Wdb  = (const float*)d_in[15];
  float* out = (float*)d_out;

  char* ws = (char*)d_ws;
  u16*   Xb   = (u16*)(ws + OFF_XB);
  u16*   WT   = (u16*)(ws + OFF_WT);
  u16*   Qb   = (u16*)(ws + OFF_QB);
  u16*   Kb   = (u16*)(ws + OFF_KB);
  u16*   Vb   = (u16*)(ws + OFF_VB);
  u16*   Cbp  = (u16*)(ws + OFF_CB);
  u16*   VbT  = (u16*)(ws + OFF_VBT);
  float* hsf  = (float*)(ws + OFF_HSF);
  float* cmx  = (float*)(ws + OFF_CMX);
  float* csm  = (float*)(ws + OFF_CSM);
  float* gmx  = (float*)(ws + OFF_GMX);
  float* gsm  = (float*)(ws + OFF_GSM);
  float* pK   = (float*)(ws + OFF_PK);
  float* pV   = (float*)(ws + OFF_PV);
  u16*   Kcb  = (u16*)(ws + OFF_KCB);
  u16*   VcT  = (u16*)(ws + OFF_VCT);
  float* biasAll = (float*)(ws + OFF_BIAS);
  float* pstatV  = (float*)(ws + OFF_PSV);

  cvt_x_kernel<<<dim3(4096), dim3(256), 0, stream>>>(X, Xb);
  transpose_all<<<dim3(1159), dim3(256), 0, stream>>>(Wq, Wk, Wv, Wd, Wo,
                                                      Wqb, Wkb, Wvb, Wdb, WT, biasAll);

  gemm_qkvh<<<dim3(1792), dim3(256), 0, stream>>>(Xb, WT, biasAll, Qb, Kb, Vb,
                                                  hsf, cmx, csm, pstatV);

  ln_k<<<dim3(4096), dim3(256), 0, stream>>>(Kb, lnlg, lnlb);
  transpose_ln_v<<<dim3(128,16), dim3(256), 0, stream>>>(Vb, pstatV, lnlg, lnlb, VbT);

  smax_comb<<<dim3(2), dim3(256), 0, stream>>>(cmx, csm, gmx, gsm);

  cmp2_kernel<<<dim3(32,16), dim3(256), 0, stream>>>(hsf, gmx, gsm, Kb, Vb, pstatV,
                                                     lnlg, lnlb, pK, pV);
  ln_c_kernel<<<dim3(64), dim3(256), 0, stream>>>(pK, pV, lnsg, lnsb, Kcb, VcT);

  attn2_kernel<<<dim3(64,8,2), dim3(512), 0, stream>>>(Qb, Kb, Kcb, VbT, VcT, Cbp);

  gemm_out<<<dim3(512), dim3(256), 0, stream>>>(Cbp, WT + (size_t)1792*512, Wob, out);
}